// Round 4
// baseline (533.609 us; speedup 1.0000x reference)
//
#include <hip/hip_runtime.h>
#include <cstddef>
#include <math.h>

#define BB 64
#define DD 2048
#define HH 2048
#define BD (BB*DD)   // 131072
#define WN (2048*2048)

typedef unsigned short u16;
typedef __attribute__((ext_vector_type(8))) short bf16x8;
typedef __attribute__((ext_vector_type(4))) float f32x4;
typedef __attribute__((ext_vector_type(4))) float f4;

__device__ __forceinline__ u16 f2b(float x) {
    union { float f; unsigned u; } v; v.f = x;
    unsigned r = v.u + 0x7FFFu + ((v.u >> 16) & 1u);
    return (u16)(r >> 16);
}

__device__ __forceinline__ void gload16(const void* g, void* l) {
    __builtin_amdgcn_global_load_lds(
        (__attribute__((address_space(1))) void*)g,
        (__attribute__((address_space(3))) void*)l, 16, 0, 0);
}

// ===========================================================================
// bf16 path
// ===========================================================================

// ---- convert 5 weights f32[k][n] -> bf16 transposed Wt[n][k] (z=0..4);
//      z==5: plain convert z f32 -> bf16
__global__ __launch_bounds__(256) void wconv(
    const float* __restrict__ W0, const float* __restrict__ W1,
    const float* __restrict__ W2, const float* __restrict__ W3,
    const float* __restrict__ W4, u16* __restrict__ wt,
    const float* __restrict__ z, u16* __restrict__ zb)
{
    int t = threadIdx.x;
    if (blockIdx.z == 5) {
        if (blockIdx.y != 0 || blockIdx.x >= 32) return;
        int i0 = blockIdx.x * 4096 + t * 16;
        u16 o[16];
#pragma unroll
        for (int q = 0; q < 4; ++q) {
            float4 f = *(const float4*)&z[i0 + q * 4];
            o[q*4+0] = f2b(f.x); o[q*4+1] = f2b(f.y);
            o[q*4+2] = f2b(f.z); o[q*4+3] = f2b(f.w);
        }
        *(bf16x8*)&zb[i0]     = *(bf16x8*)&o[0];
        *(bf16x8*)&zb[i0 + 8] = *(bf16x8*)&o[8];
        return;
    }
    const float* W;
    switch (blockIdx.z) {
        case 0: W = W0; break; case 1: W = W1; break;
        case 2: W = W2; break; case 3: W = W3; break;
        default: W = W4; break;
    }
    u16* T = wt + (size_t)blockIdx.z * WN;

    __shared__ u16 tile[64][66];
    int k0 = blockIdx.x * 64, n0 = blockIdx.y * 64;
    {   // read phase
        int r = t >> 2, c0 = (t & 3) * 16;
        const float* src = W + (size_t)(k0 + r) * DD + n0 + c0;
#pragma unroll
        for (int q = 0; q < 4; ++q) {
            float4 f = *(const float4*)(src + q * 4);
            tile[r][c0 + q*4 + 0] = f2b(f.x);
            tile[r][c0 + q*4 + 1] = f2b(f.y);
            tile[r][c0 + q*4 + 2] = f2b(f.z);
            tile[r][c0 + q*4 + 3] = f2b(f.w);
        }
    }
    __syncthreads();
    {   // write phase (transposed)
        int rn = t >> 2, ck = (t & 3) * 16;
        u16 o[16];
#pragma unroll
        for (int j = 0; j < 16; ++j) o[j] = tile[ck + j][rn];
        u16* dst = T + (size_t)(n0 + rn) * DD + k0 + ck;
        *(bf16x8*)dst       = *(bf16x8*)&o[0];
        *(bf16x8*)(dst + 8) = *(bf16x8*)&o[8];
    }
}

// ---- MFMA GEMM body: 64x64 tile, double-buffered LDS, swizzled fragments.
// LDS chunk slot = chunk ^ ((row>>1)&3)  (applied on global source; LDS dest
// linear as required by global_load_lds). Read applies the same XOR.
__device__ __forceinline__ void gemm_bf16_body(
    const u16* __restrict__ A, const u16* __restrict__ Wt,
    float* __restrict__ P, int kc)
{
    __shared__ u16 Als[2][64 * 32];
    __shared__ u16 Wls[2][64 * 32];
    const int t = threadIdx.x, w = t >> 6, lane = t & 63;
    const int n0 = blockIdx.x * 64;
    const int k0 = blockIdx.y * kc;

    f32x4 acc[4];
#pragma unroll
    for (int mt = 0; mt < 4; ++mt) acc[mt] = (f32x4){0.f, 0.f, 0.f, 0.f};

    // staging: lane L -> LDS slot L (row L>>2, slot L&3); source chunk
    // c_src = (L&3) ^ f(row),  f(r) = (r>>1)&3
    const int srow = lane >> 2;
    const int csrc = (lane & 3) ^ ((lane >> 3) & 3);
    const u16* gA = A  + (size_t)(w * 16 + srow) * DD + k0 + csrc * 8;
    const u16* gW = Wt + (size_t)(n0 + w * 16 + srow) * DD + k0 + csrc * 8;

    const int lane15 = lane & 15;
    const int cread  = lane >> 4;        // 0..3
    const int swz    = (cread ^ ((lane15 >> 1) & 3)) << 3;  // halves offset

    const int nt = kc >> 5;
    gload16(gA, &Als[0][w * 512]);
    gload16(gW, &Wls[0][w * 512]);
    __syncthreads();

    for (int it = 0; it < nt; ++it) {
        const int cur = it & 1;
        if (it + 1 < nt) {
            gload16(gA + (size_t)(it + 1) * 32, &Als[cur ^ 1][w * 512]);
            gload16(gW + (size_t)(it + 1) * 32, &Wls[cur ^ 1][w * 512]);
        }
        // rows are mt*16+lane15 / w*16+lane15; (row>>1)&3 == (lane15>>1)&3
        bf16x8 bfrag = *(const bf16x8*)&Wls[cur][(w * 16 + lane15) * 32 + swz];
#pragma unroll
        for (int mt = 0; mt < 4; ++mt) {
            bf16x8 afrag = *(const bf16x8*)&Als[cur][(mt * 16 + lane15) * 32 + swz];
            acc[mt] = __builtin_amdgcn_mfma_f32_16x16x32_bf16(
                afrag, bfrag, acc[mt], 0, 0, 0);
        }
        __syncthreads();
    }

    const int col = n0 + w * 16 + lane15;
    const int r4 = (lane >> 4) * 4;
#pragma unroll
    for (int mt = 0; mt < 4; ++mt)
#pragma unroll
        for (int j = 0; j < 4; ++j)
            P[(size_t)(mt * 16 + r4 + j) * DD + col] = acc[mt][j];
}

__global__ __launch_bounds__(256) void gemm_bf16_single(
    const u16* __restrict__ A, const u16* __restrict__ Wt,
    float* __restrict__ part, int kc)
{
    float* P = part + (size_t)blockIdx.y * 64 * DD;
    gemm_bf16_body(A, Wt, P, kc);
}

__global__ __launch_bounds__(256) void gemm_bf16_kv(
    const u16* __restrict__ A, const u16* __restrict__ Wkt,
    const u16* __restrict__ Wvt, float* __restrict__ p0,
    float* __restrict__ p1, int kc)
{
    const u16* Wt = blockIdx.z ? Wvt : Wkt;
    float* P = (blockIdx.z ? p1 : p0) + (size_t)blockIdx.y * 64 * DD;
    gemm_bf16_body(A, Wt, P, kc);
}

__global__ __launch_bounds__(256) void gemm_bf16_q(
    const u16* __restrict__ zb, const u16* __restrict__ dzb,
    const u16* __restrict__ Wqt, float* __restrict__ part, int kc)
{
    const u16* A = blockIdx.z ? dzb : zb;
    float* P = part + ((size_t)blockIdx.y * 128 + blockIdx.z * 64) * DD;
    gemm_bf16_body(A, Wqt, P, kc);
}

// ---- epilogues (bf16 path)
__global__ __launch_bounds__(256) void ep_h(
    const float* __restrict__ p, const float* __restrict__ b1,
    u16* __restrict__ hb, int KS)
{
    int i = blockIdx.x * 256 + threadIdx.x;
    float s = b1[i & (DD - 1)];
    for (int ks = 0; ks < KS; ++ks) s += p[(size_t)ks * BD + i];
    hb[i] = f2b(tanhf(s));
}

__global__ __launch_bounds__(256) void ep_dz(
    const float* __restrict__ p, const float* __restrict__ b2,
    float* __restrict__ dz, u16* __restrict__ dzb, int KS)
{
    int i = blockIdx.x * 256 + threadIdx.x;
    float s = b2[i & (DD - 1)];
    for (int ks = 0; ks < KS; ++ks) s += p[(size_t)ks * BD + i];
    dz[i]  = s;
    dzb[i] = f2b(s);
}

__global__ __launch_bounds__(256) void ep_kv(
    const float* __restrict__ pk, const float* __restrict__ pv,
    const float* __restrict__ bk, const float* __restrict__ bv,
    float* __restrict__ dKo, float* __restrict__ vo, int KS)
{
    int i = blockIdx.x * 256 + threadIdx.x;
    int d = i & (DD - 1);
    float sk = 0.f, sv = 0.f;
    for (int ks = 0; ks < KS; ++ks) {
        sk += pk[(size_t)ks * BD + i];
        sv += pv[(size_t)ks * BD + i];
    }
    dKo[i] = expf(sk + bk[d]);
    vo[i]  = sv + bv[d];
}

__global__ __launch_bounds__(256) void ep_q_dq(
    const float* __restrict__ pq, const float* __restrict__ bq,
    float* __restrict__ qo, float* __restrict__ dqo, int KS)
{
    int i = blockIdx.x * 256 + threadIdx.x;
    int b = i >> 11, d = i & (DD - 1);
    float sq = 0.f, sd = 0.f;
    for (int ks = 0; ks < KS; ++ks) {
        const float* P = pq + (size_t)ks * (128 * DD);
        sq += P[(size_t)b * DD + d];
        sd += P[(size_t)(b + 64) * DD + d];
    }
    float bb = bq[d];
    float qv = expf(sq + bb);
    qo[i]  = qv;
    dqo[i] = qv * (sd + bb);
}

// ===========================================================================
// f32 fallback GEMM path (used only if d_ws is small)
// ===========================================================================
template<int MT>
__device__ __forceinline__ void gemm_body_f32(
    const float* __restrict__ A0, const float* __restrict__ A1,
    const float* __restrict__ W, float* __restrict__ part, int kc)
{
    constexpr int KC = 32;
    constexpr int RT = MT / 16;
    __shared__ float As[KC][MT];
    __shared__ float Ws[KC][64];

    const int t  = threadIdx.x;
    const int n0 = blockIdx.x * 64;
    const int k0 = blockIdx.y * kc;
    const int i  = t >> 4;
    const int j  = t & 15;

    float acc[RT][4];
#pragma unroll
    for (int r = 0; r < RT; ++r)
#pragma unroll
        for (int c = 0; c < 4; ++c) acc[r][c] = 0.f;

    for (int kk0 = 0; kk0 < kc; kk0 += KC) {
        {
            int kk = t >> 3;
            int nn = (t & 7) << 3;
            const float* s = W + (size_t)(k0 + kk0 + kk) * DD + n0 + nn;
            *(float4*)&Ws[kk][nn]     = *(const float4*)s;
            *(float4*)&Ws[kk][nn + 4] = *(const float4*)(s + 4);
        }
        if constexpr (MT == 64) {
            int m  = t & 63;
            int kb = (t >> 6) << 3;
            const float* s = A0 + (size_t)m * DD + k0 + kk0 + kb;
            float4 a0 = *(const float4*)s;
            float4 a1 = *(const float4*)(s + 4);
            As[kb+0][m] = a0.x; As[kb+1][m] = a0.y;
            As[kb+2][m] = a0.z; As[kb+3][m] = a0.w;
            As[kb+4][m] = a1.x; As[kb+5][m] = a1.y;
            As[kb+6][m] = a1.z; As[kb+7][m] = a1.w;
        } else {
            int m  = t & 127;
            int kb = (t >> 7) << 4;
            const float* base = (m < 64) ? (A0 + (size_t)m * DD)
                                         : (A1 + (size_t)(m - 64) * DD);
            const float* s = base + k0 + kk0 + kb;
#pragma unroll
            for (int p = 0; p < 4; ++p) {
                float4 av = *(const float4*)(s + p * 4);
                As[kb+p*4+0][m] = av.x; As[kb+p*4+1][m] = av.y;
                As[kb+p*4+2][m] = av.z; As[kb+p*4+3][m] = av.w;
            }
        }
        __syncthreads();
#pragma unroll
        for (int kk = 0; kk < KC; ++kk) {
            float4 wv = *(float4*)&Ws[kk][j << 2];
#pragma unroll
            for (int rq = 0; rq < RT / 4; ++rq) {
                float4 av = *(float4*)&As[kk][i * RT + rq * 4];
                acc[rq*4+0][0] = fmaf(av.x, wv.x, acc[rq*4+0][0]);
                acc[rq*4+0][1] = fmaf(av.x, wv.y, acc[rq*4+0][1]);
                acc[rq*4+0][2] = fmaf(av.x, wv.z, acc[rq*4+0][2]);
                acc[rq*4+0][3] = fmaf(av.x, wv.w, acc[rq*4+0][3]);
                acc[rq*4+1][0] = fmaf(av.y, wv.x, acc[rq*4+1][0]);
                acc[rq*4+1][1] = fmaf(av.y, wv.y, acc[rq*4+1][1]);
                acc[rq*4+1][2] = fmaf(av.y, wv.z, acc[rq*4+1][2]);
                acc[rq*4+1][3] = fmaf(av.y, wv.w, acc[rq*4+1][3]);
                acc[rq*4+2][0] = fmaf(av.z, wv.x, acc[rq*4+2][0]);
                acc[rq*4+2][1] = fmaf(av.z, wv.y, acc[rq*4+2][1]);
                acc[rq*4+2][2] = fmaf(av.z, wv.z, acc[rq*4+2][2]);
                acc[rq*4+2][3] = fmaf(av.z, wv.w, acc[rq*4+2][3]);
                acc[rq*4+3][0] = fmaf(av.w, wv.x, acc[rq*4+3][0]);
                acc[rq*4+3][1] = fmaf(av.w, wv.y, acc[rq*4+3][1]);
                acc[rq*4+3][2] = fmaf(av.w, wv.z, acc[rq*4+3][2]);
                acc[rq*4+3][3] = fmaf(av.w, wv.w, acc[rq*4+3][3]);
            }
        }
        __syncthreads();
    }

    float* P = part + (size_t)blockIdx.y * MT * DD + n0 + (j << 2);
#pragma unroll
    for (int r = 0; r < RT; ++r)
        *(float4*)&P[(size_t)(i * RT + r) * DD] =
            make_float4(acc[r][0], acc[r][1], acc[r][2], acc[r][3]);
}

__global__ __launch_bounds__(256) void gemm64(
    const float* __restrict__ A, const float* __restrict__ W,
    float* __restrict__ part, int kc)
{ gemm_body_f32<64>(A, A, W, part, kc); }

__global__ __launch_bounds__(256) void gemm64_z2(
    const float* __restrict__ A,
    const float* __restrict__ W0, const float* __restrict__ W1,
    float* __restrict__ p0, float* __restrict__ p1, int kc)
{
    const float* W = blockIdx.z ? W1 : W0;
    float*       P = blockIdx.z ? p1 : p0;
    gemm_body_f32<64>(A, A, W, P, kc);
}

__global__ __launch_bounds__(256) void gemm128(
    const float* __restrict__ A0, const float* __restrict__ A1,
    const float* __restrict__ W, float* __restrict__ part, int kc)
{ gemm_body_f32<128>(A0, A1, W, part, kc); }

__global__ __launch_bounds__(256) void epilogue_f32(
    const float* __restrict__ part, const float* __restrict__ bias,
    float* __restrict__ out, int act, int KS)
{
    int i = blockIdx.x * 256 + threadIdx.x;
    float s = bias[i & (DD - 1)];
    for (int ks = 0; ks < KS; ++ks) s += part[(size_t)ks * BD + i];
    if (act == 1) s = tanhf(s);
    out[i] = s;
}

// ===========================================================================
// shared tail kernels
// ===========================================================================
__global__ __launch_bounds__(256) void reduce_a_da(
    const float* __restrict__ q, const float* __restrict__ dK,
    const float* __restrict__ dq, const float* __restrict__ Kin,
    float* __restrict__ a_ws, float* __restrict__ da_out)
{
    int b = blockIdx.x;
    int t = threadIdx.x;
    const float* qb  = q   + (size_t)b * DD;
    const float* dKb = dK  + (size_t)b * DD;
    const float* dqb = dq  + (size_t)b * DD;
    const float* Kb  = Kin + (size_t)b * DD;

    float s1 = 0.f, s2 = 0.f;
    for (int i = t; i < DD; i += 256) {
        s1 = fmaf(qb[i],  dKb[i], s1);
        s2 = fmaf(dqb[i], Kb[i],  s2);
    }
#pragma unroll
    for (int off = 32; off; off >>= 1) {
        s1 += __shfl_down(s1, off);
        s2 += __shfl_down(s2, off);
    }
    __shared__ float r1[4], r2[4];
    if ((t & 63) == 0) { r1[t >> 6] = s1; r2[t >> 6] = s2; }
    __syncthreads();
    if (t == 0) {
        float a  = r1[0] + r1[1] + r1[2] + r1[3];
        float k2 = r2[0] + r2[1] + r2[2] + r2[3];
        a_ws[b]   = a;
        da_out[b] = a + k2;
    }
}

// round-2 structure: wave-per-row, plain loads/stores, per-row reduce
__global__ __launch_bounds__(256) void fused_dv_dc(
    const float* __restrict__ V, const float* __restrict__ v,
    const float* __restrict__ dK, const float* __restrict__ dq,
    const float* __restrict__ a, float* __restrict__ dV,
    float* __restrict__ dc)
{
    int b     = blockIdx.x >> 5;
    int chunk = blockIdx.x & 31;
    int wave  = threadIdx.x >> 6;
    int lane  = threadIdx.x & 63;

    const f4* dK4 = (const f4*)(dK + ((size_t)b << 11));
    const f4* dq4 = (const f4*)(dq + ((size_t)b << 11));
    f4 dKr[8], dqr[8];
#pragma unroll
    for (int u = 0; u < 8; ++u) {
        dKr[u] = dK4[u * 64 + lane];
        dqr[u] = dq4[u * 64 + lane];
    }
    float ab = a[b];

    int row0 = chunk * 64 + wave * 16;
    for (int rr = 0; rr < 16; ++rr) {
        int row = row0 + rr;
        size_t off = ((size_t)((b << 11) | row)) << 11;
        const f4* V4  = (const f4*)(V  + off);
        f4*       dV4 = (f4*)(dV + off);

        float dot = 0.f;
        float vr = v[((size_t)b << 11) + row];
#pragma unroll
        for (int u = 0; u < 8; ++u) {
            f4 Vv = V4[u * 64 + lane];
            dot += Vv[0] * dqr[u][0] + Vv[1] * dqr[u][1]
                 + Vv[2] * dqr[u][2] + Vv[3] * dqr[u][3];
            f4 o = vr * dKr[u];
            dV4[u * 64 + lane] = o;
        }
#pragma unroll
        for (int s = 32; s; s >>= 1) dot += __shfl_down(dot, s);
        if (lane == 0) dc[((size_t)b << 11) + row] = vr * ab + dot;
    }
}

// ===========================================================================
extern "C" void kernel_launch(void* const* d_in, const int* in_sizes, int n_in,
                              void* d_out, int out_size, void* d_ws, size_t ws_size,
                              hipStream_t stream)
{
    const float* z   = (const float*)d_in[1];
    const float* Kin = (const float*)d_in[2];
    const float* Vin = (const float*)d_in[3];
    const float* Wq  = (const float*)d_in[4];
    const float* bq  = (const float*)d_in[5];
    const float* Wk  = (const float*)d_in[6];
    const float* bk  = (const float*)d_in[7];
    const float* Wv  = (const float*)d_in[8];
    const float* bv  = (const float*)d_in[9];
    const float* W1  = (const float*)d_in[10];
    const float* b1  = (const float*)d_in[11];
    const float* W2  = (const float*)d_in[12];
    const float* b2  = (const float*)d_in[13];

    float* out   = (float*)d_out;
    float* o_dz  = out;
    float* o_da  = out + BD;
    float* o_dc  = out + BD + BB;
    float* o_dK  = out + 2 * BD + BB;
    float* o_dV  = out + 3 * BD + BB;

    float* ws    = (float*)d_ws;
    float* ws_v  = ws;
    float* ws_q  = ws + BD;
    float* ws_dq = ws + 2 * BD;
    float* ws_a  = ws + 3 * BD;          // 64
    float* ws_h  = ws + 3 * BD + 64;     // fallback only
    u16*   zb    = (u16*)(ws + 4 * BD + 64);
    u16*   hb    = zb + BD;
    u16*   dzb   = hb + BD;
    u16*   wt    = dzb + BD;             // 5 * WN u16
    float* poolb = (float*)(wt + 5ull * WN);

    const size_t pre_fl = 4ull * BD + 64 + (3ull * BD + 5ull * WN) / 2;

    int KS = 0;
    for (int ks = 16; ks >= 4; ks >>= 1)
        if ((pre_fl + 2ull * ks * BD) * 4ull <= ws_size) { KS = ks; break; }

    dim3 blk(256);
    dim3 gE(BD / 256);

    if (KS) {
        // ------------------- bf16 MFMA path -------------------
        int kc = DD / KS;
        float* p0 = poolb;
        float* p1 = poolb + (size_t)KS * BD;

        dim3 gW(32, 32, 6);
        dim3 gG(32, KS);
        dim3 gG2(32, KS, 2);

        wconv<<<gW, blk, 0, stream>>>(W1, W2, Wk, Wv, Wq, wt, z, zb);

        u16* W1t = wt;
        u16* W2t = wt + 1ull * WN;
        u16* Wkt = wt + 2ull * WN;
        u16* Wvt = wt + 3ull * WN;
        u16* Wqt = wt + 4ull * WN;

        // 1) h = tanh(z @ W1 + b1)
        gemm_bf16_single<<<gG, blk, 0, stream>>>(zb, W1t, p0, kc);
        ep_h<<<gE, blk, 0, stream>>>(p0, b1, hb, KS);

        // 2) dz = h @ W2 + b2
        gemm_bf16_single<<<gG, blk, 0, stream>>>(hb, W2t, p0, kc);
        ep_dz<<<gE, blk, 0, stream>>>(p0, b2, o_dz, dzb, KS);

        // 3) dK = exp(z@Wk+bk); v = z@Wv+bv
        gemm_bf16_kv<<<gG2, blk, 0, stream>>>(zb, Wkt, Wvt, p0, p1, kc);
        ep_kv<<<gE, blk, 0, stream>>>(p0, p1, bk, bv, o_dK, ws_v, KS);

        // 4) [z; dz] @ Wq -> q, dq
        gemm_bf16_q<<<gG2, blk, 0, stream>>>(zb, dzb, Wqt, p0, kc);
        ep_q_dq<<<gE, blk, 0, stream>>>(p0, bq, ws_q, ws_dq, KS);
    } else {
        // ------------------- f32 fallback path -------------------
        float* pool = ws + 4 * BD + 64;
        int KSf = 16;
        while (KSf > 1 &&
               ((size_t)(4 * BD + 64) + 2ull * KSf * BD) * 4ull > ws_size)
            KSf >>= 1;
        int kc = DD / KSf;
        float* p0 = pool;
        float* p1 = pool + (size_t)KSf * BD;

        dim3 gG(DD / 64, KSf);
        dim3 gG2(DD / 64, KSf, 2);

        gemm64<<<gG, blk, 0, stream>>>(z, W1, p0, kc);
        epilogue_f32<<<gE, blk, 0, stream>>>(p0, b1, ws_h, 1, KSf);

        gemm64<<<gG, blk, 0, stream>>>(ws_h, W2, p0, kc);
        epilogue_f32<<<gE, blk, 0, stream>>>(p0, b2, o_dz, 0, KSf);

        gemm64_z2<<<gG2, blk, 0, stream>>>(z, Wk, Wv, p0, p1, kc);
        ep_kv<<<gE, blk, 0, stream>>>(p0, p1, bk, bv, o_dK, ws_v, KSf);

        gemm128<<<gG, blk, 0, stream>>>(z, o_dz, Wq, p0, kc);
        ep_q_dq<<<gE, blk, 0, stream>>>(p0, bq, ws_q, ws_dq, KSf);
    }

    // 5) a = q . dK ; da = a + dq . K
    reduce_a_da<<<dim3(BB), blk, 0, stream>>>(ws_q, o_dK, ws_dq, Kin, ws_a, o_da);

    // 6) dV = outer(v, dK); dc = v*a + V @ dq
    fused_dv_dc<<<dim3(BB * 32), blk, 0, stream>>>(Vin, ws_v, o_dK, ws_dq, ws_a,
                                                   o_dV, o_dc);
}

// Round 5
// 445.687 us; speedup vs baseline: 1.1973x; 1.1973x over previous
//
#include <hip/hip_runtime.h>
#include <cstddef>
#include <math.h>

#define BB 64
#define DD 2048
#define HH 2048
#define BD (BB*DD)   // 131072
#define WN (2048*2048)

typedef unsigned short u16;
typedef __attribute__((ext_vector_type(8))) short bf16x8;
typedef __attribute__((ext_vector_type(4))) float f32x4;
typedef __attribute__((ext_vector_type(4))) float f4;

__device__ __forceinline__ u16 f2b(float x) {
    union { float f; unsigned u; } v; v.f = x;
    unsigned r = v.u + 0x7FFFu + ((v.u >> 16) & 1u);
    return (u16)(r >> 16);
}

__device__ __forceinline__ void gload16(const void* g, void* l) {
    __builtin_amdgcn_global_load_lds(
        (__attribute__((address_space(1))) void*)g,
        (__attribute__((address_space(3))) void*)l, 16, 0, 0);
}

// ===========================================================================
// bf16 path
// ===========================================================================

// ---- convert 5 weights f32[k][n] -> bf16 transposed Wt[n][k] (z=0..4);
//      z==5: plain convert z f32 -> bf16
__global__ __launch_bounds__(256) void wconv(
    const float* __restrict__ W0, const float* __restrict__ W1,
    const float* __restrict__ W2, const float* __restrict__ W3,
    const float* __restrict__ W4, u16* __restrict__ wt,
    const float* __restrict__ z, u16* __restrict__ zb)
{
    int t = threadIdx.x;
    if (blockIdx.z == 5) {
        if (blockIdx.y != 0 || blockIdx.x >= 32) return;
        int i0 = blockIdx.x * 4096 + t * 16;
        u16 o[16];
#pragma unroll
        for (int q = 0; q < 4; ++q) {
            float4 f = *(const float4*)&z[i0 + q * 4];
            o[q*4+0] = f2b(f.x); o[q*4+1] = f2b(f.y);
            o[q*4+2] = f2b(f.z); o[q*4+3] = f2b(f.w);
        }
        *(bf16x8*)&zb[i0]     = *(bf16x8*)&o[0];
        *(bf16x8*)&zb[i0 + 8] = *(bf16x8*)&o[8];
        return;
    }
    const float* W;
    switch (blockIdx.z) {
        case 0: W = W0; break; case 1: W = W1; break;
        case 2: W = W2; break; case 3: W = W3; break;
        default: W = W4; break;
    }
    u16* T = wt + (size_t)blockIdx.z * WN;

    __shared__ u16 tile[64][66];
    int k0 = blockIdx.x * 64, n0 = blockIdx.y * 64;
    {   // read phase: coalesced rows of W
        int r = t >> 2, c0 = (t & 3) * 16;
        const float* src = W + (size_t)(k0 + r) * DD + n0 + c0;
#pragma unroll
        for (int q = 0; q < 4; ++q) {
            float4 f = *(const float4*)(src + q * 4);
            tile[r][c0 + q*4 + 0] = f2b(f.x);
            tile[r][c0 + q*4 + 1] = f2b(f.y);
            tile[r][c0 + q*4 + 2] = f2b(f.z);
            tile[r][c0 + q*4 + 3] = f2b(f.w);
        }
    }
    __syncthreads();
    {   // write phase: coalesced rows of Wt (= columns of W)
        int rn = t >> 2, ck = (t & 3) * 16;
        u16 o[16];
#pragma unroll
        for (int j = 0; j < 16; ++j) o[j] = tile[ck + j][rn];
        u16* dst = T + (size_t)(n0 + rn) * DD + k0 + ck;
        *(bf16x8*)dst       = *(bf16x8*)&o[0];
        *(bf16x8*)(dst + 8) = *(bf16x8*)&o[8];
    }
}

// ---- MFMA GEMM body (R3 structure): 64x64 tile, single-buffered LDS
__device__ __forceinline__ void gemm_bf16_body(
    const u16* __restrict__ A, const u16* __restrict__ Wt,
    float* __restrict__ P, int kc)
{
    __shared__ u16 Als[64 * 32];
    __shared__ u16 Wls[64 * 32];
    const int t = threadIdx.x, w = t >> 6, lane = t & 63;
    const int n0 = blockIdx.x * 64;
    const int k0 = blockIdx.y * kc;

    f32x4 acc[4];
#pragma unroll
    for (int mt = 0; mt < 4; ++mt) acc[mt] = (f32x4){0.f, 0.f, 0.f, 0.f};

    const int srow = lane >> 2;          // 0..15
    const int sk   = (lane & 3) * 8;     // ushort offset (16B chunks)
    const u16* gA = A  + (size_t)(w * 16 + srow) * DD + k0 + sk;
    const u16* gW = Wt + (size_t)(n0 + w * 16 + srow) * DD + k0 + sk;
    u16* lA = &Als[w * 512];             // wave-uniform; HW adds lane*16B
    u16* lW = &Wls[w * 512];

    const int lane15 = lane & 15;
    const int k8 = (lane >> 4) * 8;

    for (int kk = 0; kk < kc; kk += 32) {
        gload16(gA, lA);
        gload16(gW, lW);
        gA += 32; gW += 32;
        __syncthreads();

        bf16x8 bfrag = *(const bf16x8*)&Wls[(w * 16 + lane15) * 32 + k8];
#pragma unroll
        for (int mt = 0; mt < 4; ++mt) {
            bf16x8 afrag = *(const bf16x8*)&Als[(mt * 16 + lane15) * 32 + k8];
            acc[mt] = __builtin_amdgcn_mfma_f32_16x16x32_bf16(
                afrag, bfrag, acc[mt], 0, 0, 0);
        }
        __syncthreads();
    }

    const int col = n0 + w * 16 + lane15;
    const int r4 = (lane >> 4) * 4;
#pragma unroll
    for (int mt = 0; mt < 4; ++mt)
#pragma unroll
        for (int j = 0; j < 4; ++j)
            P[(size_t)(mt * 16 + r4 + j) * DD + col] = acc[mt][j];
}

__global__ __launch_bounds__(256) void gemm_bf16_single(
    const u16* __restrict__ A, const u16* __restrict__ Wt,
    float* __restrict__ part, int kc)
{
    float* P = part + (size_t)blockIdx.y * 64 * DD;
    gemm_bf16_body(A, Wt, P, kc);
}

__global__ __launch_bounds__(256) void gemm_bf16_kv(
    const u16* __restrict__ A, const u16* __restrict__ Wkt,
    const u16* __restrict__ Wvt, float* __restrict__ p0,
    float* __restrict__ p1, int kc)
{
    const u16* Wt = blockIdx.z ? Wvt : Wkt;
    float* P = (blockIdx.z ? p1 : p0) + (size_t)blockIdx.y * 64 * DD;
    gemm_bf16_body(A, Wt, P, kc);
}

__global__ __launch_bounds__(256) void gemm_bf16_q(
    const u16* __restrict__ zb, const u16* __restrict__ dzb,
    const u16* __restrict__ Wqt, float* __restrict__ part, int kc)
{
    const u16* A = blockIdx.z ? dzb : zb;
    float* P = part + ((size_t)blockIdx.y * 128 + blockIdx.z * 64) * DD;
    gemm_bf16_body(A, Wqt, P, kc);
}

// ---- epilogues (bf16 path)
__global__ __launch_bounds__(256) void ep_h(
    const float* __restrict__ p, const float* __restrict__ b1,
    u16* __restrict__ hb, int KS)
{
    int i = blockIdx.x * 256 + threadIdx.x;
    float s = b1[i & (DD - 1)];
    for (int ks = 0; ks < KS; ++ks) s += p[(size_t)ks * BD + i];
    hb[i] = f2b(tanhf(s));
}

__global__ __launch_bounds__(256) void ep_dz(
    const float* __restrict__ p, const float* __restrict__ b2,
    float* __restrict__ dz, u16* __restrict__ dzb, int KS)
{
    int i = blockIdx.x * 256 + threadIdx.x;
    float s = b2[i & (DD - 1)];
    for (int ks = 0; ks < KS; ++ks) s += p[(size_t)ks * BD + i];
    dz[i]  = s;
    dzb[i] = f2b(s);
}

__global__ __launch_bounds__(256) void ep_kv(
    const float* __restrict__ pk, const float* __restrict__ pv,
    const float* __restrict__ bk, const float* __restrict__ bv,
    float* __restrict__ dKo, float* __restrict__ vo, int KS)
{
    int i = blockIdx.x * 256 + threadIdx.x;
    int d = i & (DD - 1);
    float sk = 0.f, sv = 0.f;
    for (int ks = 0; ks < KS; ++ks) {
        sk += pk[(size_t)ks * BD + i];
        sv += pv[(size_t)ks * BD + i];
    }
    dKo[i] = expf(sk + bk[d]);
    vo[i]  = sv + bv[d];
}

__global__ __launch_bounds__(256) void ep_q_dq(
    const float* __restrict__ pq, const float* __restrict__ bq,
    float* __restrict__ qo, float* __restrict__ dqo, int KS)
{
    int i = blockIdx.x * 256 + threadIdx.x;
    int b = i >> 11, d = i & (DD - 1);
    float sq = 0.f, sd = 0.f;
    for (int ks = 0; ks < KS; ++ks) {
        const float* P = pq + (size_t)ks * (128 * DD);
        sq += P[(size_t)b * DD + d];
        sd += P[(size_t)(b + 64) * DD + d];
    }
    float bb = bq[d];
    float qv = expf(sq + bb);
    qo[i]  = qv;
    dqo[i] = qv * (sd + bb);
}

// ===========================================================================
// f32 fallback GEMM path (used only if d_ws is small)
// ===========================================================================
template<int MT>
__device__ __forceinline__ void gemm_body_f32(
    const float* __restrict__ A0, const float* __restrict__ A1,
    const float* __restrict__ W, float* __restrict__ part, int kc)
{
    constexpr int KC = 32;
    constexpr int RT = MT / 16;
    __shared__ float As[KC][MT];
    __shared__ float Ws[KC][64];

    const int t  = threadIdx.x;
    const int n0 = blockIdx.x * 64;
    const int k0 = blockIdx.y * kc;
    const int i  = t >> 4;
    const int j  = t & 15;

    float acc[RT][4];
#pragma unroll
    for (int r = 0; r < RT; ++r)
#pragma unroll
        for (int c = 0; c < 4; ++c) acc[r][c] = 0.f;

    for (int kk0 = 0; kk0 < kc; kk0 += KC) {
        {
            int kk = t >> 3;
            int nn = (t & 7) << 3;
            const float* s = W + (size_t)(k0 + kk0 + kk) * DD + n0 + nn;
            *(float4*)&Ws[kk][nn]     = *(const float4*)s;
            *(float4*)&Ws[kk][nn + 4] = *(const float4*)(s + 4);
        }
        if constexpr (MT == 64) {
            int m  = t & 63;
            int kb = (t >> 6) << 3;
            const float* s = A0 + (size_t)m * DD + k0 + kk0 + kb;
            float4 a0 = *(const float4*)s;
            float4 a1 = *(const float4*)(s + 4);
            As[kb+0][m] = a0.x; As[kb+1][m] = a0.y;
            As[kb+2][m] = a0.z; As[kb+3][m] = a0.w;
            As[kb+4][m] = a1.x; As[kb+5][m] = a1.y;
            As[kb+6][m] = a1.z; As[kb+7][m] = a1.w;
        } else {
            int m  = t & 127;
            int kb = (t >> 7) << 4;
            const float* base = (m < 64) ? (A0 + (size_t)m * DD)
                                         : (A1 + (size_t)(m - 64) * DD);
            const float* s = base + k0 + kk0 + kb;
#pragma unroll
            for (int p = 0; p < 4; ++p) {
                float4 av = *(const float4*)(s + p * 4);
                As[kb+p*4+0][m] = av.x; As[kb+p*4+1][m] = av.y;
                As[kb+p*4+2][m] = av.z; As[kb+p*4+3][m] = av.w;
            }
        }
        __syncthreads();
#pragma unroll
        for (int kk = 0; kk < KC; ++kk) {
            float4 wv = *(float4*)&Ws[kk][j << 2];
#pragma unroll
            for (int rq = 0; rq < RT / 4; ++rq) {
                float4 av = *(float4*)&As[kk][i * RT + rq * 4];
                acc[rq*4+0][0] = fmaf(av.x, wv.x, acc[rq*4+0][0]);
                acc[rq*4+0][1] = fmaf(av.x, wv.y, acc[rq*4+0][1]);
                acc[rq*4+0][2] = fmaf(av.x, wv.z, acc[rq*4+0][2]);
                acc[rq*4+0][3] = fmaf(av.x, wv.w, acc[rq*4+0][3]);
                acc[rq*4+1][0] = fmaf(av.y, wv.x, acc[rq*4+1][0]);
                acc[rq*4+1][1] = fmaf(av.y, wv.y, acc[rq*4+1][1]);
                acc[rq*4+1][2] = fmaf(av.y, wv.z, acc[rq*4+1][2]);
                acc[rq*4+1][3] = fmaf(av.y, wv.w, acc[rq*4+1][3]);
                acc[rq*4+2][0] = fmaf(av.z, wv.x, acc[rq*4+2][0]);
                acc[rq*4+2][1] = fmaf(av.z, wv.y, acc[rq*4+2][1]);
                acc[rq*4+2][2] = fmaf(av.z, wv.z, acc[rq*4+2][2]);
                acc[rq*4+2][3] = fmaf(av.z, wv.w, acc[rq*4+2][3]);
                acc[rq*4+3][0] = fmaf(av.w, wv.x, acc[rq*4+3][0]);
                acc[rq*4+3][1] = fmaf(av.w, wv.y, acc[rq*4+3][1]);
                acc[rq*4+3][2] = fmaf(av.w, wv.z, acc[rq*4+3][2]);
                acc[rq*4+3][3] = fmaf(av.w, wv.w, acc[rq*4+3][3]);
            }
        }
        __syncthreads();
    }

    float* P = part + (size_t)blockIdx.y * MT * DD + n0 + (j << 2);
#pragma unroll
    for (int r = 0; r < RT; ++r)
        *(float4*)&P[(size_t)(i * RT + r) * DD] =
            make_float4(acc[r][0], acc[r][1], acc[r][2], acc[r][3]);
}

__global__ __launch_bounds__(256) void gemm64(
    const float* __restrict__ A, const float* __restrict__ W,
    float* __restrict__ part, int kc)
{ gemm_body_f32<64>(A, A, W, part, kc); }

__global__ __launch_bounds__(256) void gemm64_z2(
    const float* __restrict__ A,
    const float* __restrict__ W0, const float* __restrict__ W1,
    float* __restrict__ p0, float* __restrict__ p1, int kc)
{
    const float* W = blockIdx.z ? W1 : W0;
    float*       P = blockIdx.z ? p1 : p0;
    gemm_body_f32<64>(A, A, W, P, kc);
}

__global__ __launch_bounds__(256) void gemm128(
    const float* __restrict__ A0, const float* __restrict__ A1,
    const float* __restrict__ W, float* __restrict__ part, int kc)
{ gemm_body_f32<128>(A0, A1, W, part, kc); }

__global__ __launch_bounds__(256) void epilogue_f32(
    const float* __restrict__ part, const float* __restrict__ bias,
    float* __restrict__ out, int act, int KS)
{
    int i = blockIdx.x * 256 + threadIdx.x;
    float s = bias[i & (DD - 1)];
    for (int ks = 0; ks < KS; ++ks) s += part[(size_t)ks * BD + i];
    if (act == 1) s = tanhf(s);
    out[i] = s;
}

// ===========================================================================
// shared tail kernels
// ===========================================================================
__global__ __launch_bounds__(256) void reduce_a_da(
    const float* __restrict__ q, const float* __restrict__ dK,
    const float* __restrict__ dq, const float* __restrict__ Kin,
    float* __restrict__ a_ws, float* __restrict__ da_out)
{
    int b = blockIdx.x;
    int t = threadIdx.x;
    const float* qb  = q   + (size_t)b * DD;
    const float* dKb = dK  + (size_t)b * DD;
    const float* dqb = dq  + (size_t)b * DD;
    const float* Kb  = Kin + (size_t)b * DD;

    float s1 = 0.f, s2 = 0.f;
    for (int i = t; i < DD; i += 256) {
        s1 = fmaf(qb[i],  dKb[i], s1);
        s2 = fmaf(dqb[i], Kb[i],  s2);
    }
#pragma unroll
    for (int off = 32; off; off >>= 1) {
        s1 += __shfl_down(s1, off);
        s2 += __shfl_down(s2, off);
    }
    __shared__ float r1[4], r2[4];
    if ((t & 63) == 0) { r1[t >> 6] = s1; r2[t >> 6] = s2; }
    __syncthreads();
    if (t == 0) {
        float a  = r1[0] + r1[1] + r1[2] + r1[3];
        float k2 = r2[0] + r2[1] + r2[2] + r2[3];
        a_ws[b]   = a;
        da_out[b] = a + k2;
    }
}

// ---- pure write stream: dV[b,d,e] = v[b,d] * dK[b,e]
__global__ __launch_bounds__(256) void dv_write(
    const float* __restrict__ v, const float* __restrict__ dK,
    float* __restrict__ dV)
{
    int b     = blockIdx.x >> 5;
    int chunk = blockIdx.x & 31;
    int wave  = threadIdx.x >> 6;
    int lane  = threadIdx.x & 63;

    const f4* dK4 = (const f4*)(dK + ((size_t)b << 11));
    f4 dKr[8];
#pragma unroll
    for (int u = 0; u < 8; ++u) dKr[u] = dK4[u * 64 + lane];

    int row0 = chunk * 64 + wave * 16;
    for (int rr = 0; rr < 16; ++rr) {
        int row = row0 + rr;
        float vr = v[((size_t)b << 11) + row];
        f4* dV4 = (f4*)(dV + (((size_t)((b << 11) | row)) << 11));
#pragma unroll
        for (int u = 0; u < 8; ++u) {
            f4 o = vr * dKr[u];
            __builtin_nontemporal_store(o, &dV4[u * 64 + lane]);
        }
    }
}

// ---- pure read stream: dc[b,d] = v[b,d]*a[b] + sum_e V[b,d,e]*dq[b,e]
__global__ __launch_bounds__(256) void dc_dot(
    const float* __restrict__ V, const float* __restrict__ v,
    const float* __restrict__ dq, const float* __restrict__ a,
    float* __restrict__ dc)
{
    int b     = blockIdx.x >> 5;
    int chunk = blockIdx.x & 31;
    int wave  = threadIdx.x >> 6;
    int lane  = threadIdx.x & 63;

    const f4* dq4 = (const f4*)(dq + ((size_t)b << 11));
    f4 dqr[8];
#pragma unroll
    for (int u = 0; u < 8; ++u) dqr[u] = dq4[u * 64 + lane];
    float ab = a[b];

    int row0 = chunk * 64 + wave * 16;
    for (int g = 0; g < 4; ++g) {
        float dot[4];
#pragma unroll
        for (int r2 = 0; r2 < 4; ++r2) {
            int row = row0 + g * 4 + r2;
            const f4* V4 = (const f4*)(V + (((size_t)((b << 11) | row)) << 11));
            float d = 0.f;
#pragma unroll
            for (int u = 0; u < 8; ++u) {
                f4 Vv = __builtin_nontemporal_load(&V4[u * 64 + lane]);
                d += Vv[0] * dqr[u][0] + Vv[1] * dqr[u][1]
                   + Vv[2] * dqr[u][2] + Vv[3] * dqr[u][3];
            }
            dot[r2] = d;
        }
#pragma unroll
        for (int r2 = 0; r2 < 4; ++r2) {
            float d = dot[r2];
#pragma unroll
            for (int s = 32; s; s >>= 1) d += __shfl_down(d, s);
            if (lane == 0) {
                int row = row0 + g * 4 + r2;
                dc[((size_t)b << 11) + row] =
                    v[((size_t)b << 11) + row] * ab + d;
            }
        }
    }
}

// ===========================================================================
extern "C" void kernel_launch(void* const* d_in, const int* in_sizes, int n_in,
                              void* d_out, int out_size, void* d_ws, size_t ws_size,
                              hipStream_t stream)
{
    const float* z   = (const float*)d_in[1];
    const float* Kin = (const float*)d_in[2];
    const float* Vin = (const float*)d_in[3];
    const float* Wq  = (const float*)d_in[4];
    const float* bq  = (const float*)d_in[5];
    const float* Wk  = (const float*)d_in[6];
    const float* bk  = (const float*)d_in[7];
    const float* Wv  = (const float*)d_in[8];
    const float* bv  = (const float*)d_in[9];
    const float* W1  = (const float*)d_in[10];
    const float* b1  = (const float*)d_in[11];
    const float* W2  = (const float*)d_in[12];
    const float* b2  = (const float*)d_in[13];

    float* out   = (float*)d_out;
    float* o_dz  = out;
    float* o_da  = out + BD;
    float* o_dc  = out + BD + BB;
    float* o_dK  = out + 2 * BD + BB;
    float* o_dV  = out + 3 * BD + BB;

    float* ws    = (float*)d_ws;
    float* ws_v  = ws;
    float* ws_q  = ws + BD;
    float* ws_dq = ws + 2 * BD;
    float* ws_a  = ws + 3 * BD;          // 64
    float* ws_h  = ws + 3 * BD + 64;     // fallback only
    u16*   zb    = (u16*)(ws + 4 * BD + 64);
    u16*   hb    = zb + BD;
    u16*   dzb   = hb + BD;
    u16*   wt    = dzb + BD;             // 5 * WN u16
    float* poolb = (float*)(wt + 5ull * WN);

    const size_t pre_fl = 4ull * BD + 64 + (3ull * BD + 5ull * WN) / 2;

    int KS = 0;
    for (int ks = 16; ks >= 4; ks >>= 1)
        if ((pre_fl + 2ull * ks * BD) * 4ull <= ws_size) { KS = ks; break; }

    dim3 blk(256);
    dim3 gE(BD / 256);

    if (KS) {
        // ------------------- bf16 MFMA path -------------------
        int kc = DD / KS;
        float* p0 = poolb;
        float* p1 = poolb + (size_t)KS * BD;

        dim3 gW(32, 32, 6);
        dim3 gG(32, KS);
        dim3 gG2(32, KS, 2);

        wconv<<<gW, blk, 0, stream>>>(W1, W2, Wk, Wv, Wq, wt, z, zb);

        u16* W1t = wt;
        u16* W2t = wt + 1ull * WN;
        u16* Wkt = wt + 2ull * WN;
        u16* Wvt = wt + 3ull * WN;
        u16* Wqt = wt + 4ull * WN;

        // 1) h = tanh(z @ W1 + b1)
        gemm_bf16_single<<<gG, blk, 0, stream>>>(zb, W1t, p0, kc);
        ep_h<<<gE, blk, 0, stream>>>(p0, b1, hb, KS);

        // 2) dz = h @ W2 + b2
        gemm_bf16_single<<<gG, blk, 0, stream>>>(hb, W2t, p0, kc);
        ep_dz<<<gE, blk, 0, stream>>>(p0, b2, o_dz, dzb, KS);

        // 3) dK = exp(z@Wk+bk); v = z@Wv+bv
        gemm_bf16_kv<<<gG2, blk, 0, stream>>>(zb, Wkt, Wvt, p0, p1, kc);
        ep_kv<<<gE, blk, 0, stream>>>(p0, p1, bk, bv, o_dK, ws_v, KS);

        // 3b) dV = outer(v, dK)  — pure write stream, inputs ready here
        dv_write<<<dim3(BB * 32), blk, 0, stream>>>(ws_v, o_dK, o_dV);

        // 4) [z; dz] @ Wq -> q, dq
        gemm_bf16_q<<<gG2, blk, 0, stream>>>(zb, dzb, Wqt, p0, kc);
        ep_q_dq<<<gE, blk, 0, stream>>>(p0, bq, ws_q, ws_dq, KS);
    } else {
        // ------------------- f32 fallback path -------------------
        float* pool = ws + 4 * BD + 64;
        int KSf = 16;
        while (KSf > 1 &&
               ((size_t)(4 * BD + 64) + 2ull * KSf * BD) * 4ull > ws_size)
            KSf >>= 1;
        int kc = DD / KSf;
        float* p0 = pool;
        float* p1 = pool + (size_t)KSf * BD;

        dim3 gG(DD / 64, KSf);
        dim3 gG2(DD / 64, KSf, 2);

        gemm64<<<gG, blk, 0, stream>>>(z, W1, p0, kc);
        epilogue_f32<<<gE, blk, 0, stream>>>(p0, b1, ws_h, 1, KSf);

        gemm64<<<gG, blk, 0, stream>>>(ws_h, W2, p0, kc);
        epilogue_f32<<<gE, blk, 0, stream>>>(p0, b2, o_dz, 0, KSf);

        gemm64_z2<<<gG2, blk, 0, stream>>>(z, Wk, Wv, p0, p1, kc);
        ep_kv<<<gE, blk, 0, stream>>>(p0, p1, bk, bv, o_dK, ws_v, KSf);

        dv_write<<<dim3(BB * 32), blk, 0, stream>>>(ws_v, o_dK, o_dV);

        gemm128<<<gG, blk, 0, stream>>>(z, o_dz, Wq, p0, kc);
        ep_q_dq<<<gE, blk, 0, stream>>>(p0, bq, ws_q, ws_dq, KSf);
    }

    // 5) a = q . dK ; da = a + dq . K
    reduce_a_da<<<dim3(BB), blk, 0, stream>>>(ws_q, o_dK, ws_dq, Kin, ws_a, o_da);

    // 6) dc = v*a + V @ dq  — pure read stream
    dc_dot<<<dim3(BB * 32), blk, 0, stream>>>(Vin, ws_v, ws_dq, ws_a, o_dc);
}

// Round 6
// 425.567 us; speedup vs baseline: 1.2539x; 1.0473x over previous
//
#include <hip/hip_runtime.h>
#include <cstddef>
#include <math.h>

#define BB 64
#define DD 2048
#define HH 2048
#define BD (BB*DD)   // 131072
#define WN (2048*2048)

typedef unsigned short u16;
typedef __attribute__((ext_vector_type(8))) short bf16x8;
typedef __attribute__((ext_vector_type(4))) float f32x4;
typedef __attribute__((ext_vector_type(4))) float f4;

__device__ __forceinline__ u16 f2b(float x) {
    union { float f; unsigned u; } v; v.f = x;
    unsigned r = v.u + 0x7FFFu + ((v.u >> 16) & 1u);
    return (u16)(r >> 16);
}

__device__ __forceinline__ void gload16(const void* g, void* l) {
    __builtin_amdgcn_global_load_lds(
        (__attribute__((address_space(1))) void*)g,
        (__attribute__((address_space(3))) void*)l, 16, 0, 0);
}

// ===========================================================================
// device bodies (shared-memory passed in so merged kernels can union it)
// ===========================================================================

// ---- weight tile f32[k][n] -> bf16 T[n][k]; sm is 64*66 u16
__device__ __forceinline__ void wconv_tile(
    u16* sm, const float* __restrict__ W, u16* __restrict__ T,
    int kb, int nb)
{
    int t = threadIdx.x;
    int k0 = kb * 64, n0 = nb * 64;
    {
        int r = t >> 2, c0 = (t & 3) * 16;
        const float* src = W + (size_t)(k0 + r) * DD + n0 + c0;
#pragma unroll
        for (int q = 0; q < 4; ++q) {
            float4 f = *(const float4*)(src + q * 4);
            sm[r * 66 + c0 + q*4 + 0] = f2b(f.x);
            sm[r * 66 + c0 + q*4 + 1] = f2b(f.y);
            sm[r * 66 + c0 + q*4 + 2] = f2b(f.z);
            sm[r * 66 + c0 + q*4 + 3] = f2b(f.w);
        }
    }
    __syncthreads();
    {
        int rn = t >> 2, ck = (t & 3) * 16;
        u16 o[16];
#pragma unroll
        for (int j = 0; j < 16; ++j) o[j] = sm[(ck + j) * 66 + rn];
        u16* dst = T + (size_t)(n0 + rn) * DD + k0 + ck;
        *(bf16x8*)dst       = *(bf16x8*)&o[0];
        *(bf16x8*)(dst + 8) = *(bf16x8*)&o[8];
    }
}

// ---- MFMA GEMM body: 64x64 tile; sm is 4096 u16 (A 2048 | W 2048)
__device__ __forceinline__ void gemm_bf16_body(
    u16* sm, const u16* __restrict__ A, const u16* __restrict__ Wt,
    float* __restrict__ P, int kc, int nblk, int kblk)
{
    u16* Als = sm;
    u16* Wls = sm + 2048;
    const int t = threadIdx.x, w = t >> 6, lane = t & 63;
    const int n0 = nblk * 64;
    const int k0 = kblk * kc;

    f32x4 acc[4];
#pragma unroll
    for (int mt = 0; mt < 4; ++mt) acc[mt] = (f32x4){0.f, 0.f, 0.f, 0.f};

    const int srow = lane >> 2;          // 0..15
    const int sk   = (lane & 3) * 8;     // ushort offset (16B chunks)
    const u16* gA = A  + (size_t)(w * 16 + srow) * DD + k0 + sk;
    const u16* gW = Wt + (size_t)(n0 + w * 16 + srow) * DD + k0 + sk;
    u16* lA = &Als[w * 512];             // wave-uniform; HW adds lane*16B
    u16* lW = &Wls[w * 512];

    const int lane15 = lane & 15;
    const int k8 = (lane >> 4) * 8;

    for (int kk = 0; kk < kc; kk += 32) {
        gload16(gA, lA);
        gload16(gW, lW);
        gA += 32; gW += 32;
        __syncthreads();

        bf16x8 bfrag = *(const bf16x8*)&Wls[(w * 16 + lane15) * 32 + k8];
#pragma unroll
        for (int mt = 0; mt < 4; ++mt) {
            bf16x8 afrag = *(const bf16x8*)&Als[(mt * 16 + lane15) * 32 + k8];
            acc[mt] = __builtin_amdgcn_mfma_f32_16x16x32_bf16(
                afrag, bfrag, acc[mt], 0, 0, 0);
        }
        __syncthreads();
    }

    const int col = n0 + w * 16 + lane15;
    const int r4 = (lane >> 4) * 4;
#pragma unroll
    for (int mt = 0; mt < 4; ++mt)
#pragma unroll
        for (int j = 0; j < 4; ++j)
            P[(size_t)(mt * 16 + r4 + j) * DD + col] = acc[mt][j];
}

// ---- dV row-chunk writer: dV[b, chunk*64 .. +64, :] = v ⊗ dK (nt stores)
__device__ __forceinline__ void dv_body(
    const float* __restrict__ v, const float* __restrict__ dK,
    float* __restrict__ dV, int b, int chunk)
{
    int wave = threadIdx.x >> 6;
    int lane = threadIdx.x & 63;

    const f4* dK4 = (const f4*)(dK + ((size_t)b << 11));
    f4 dKr[8];
#pragma unroll
    for (int u = 0; u < 8; ++u) dKr[u] = dK4[u * 64 + lane];

    int row0 = chunk * 64 + wave * 16;
    for (int rr = 0; rr < 16; ++rr) {
        int row = row0 + rr;
        float vr = v[((size_t)b << 11) + row];
        f4* dV4 = (f4*)(dV + (((size_t)((b << 11) | row)) << 11));
#pragma unroll
        for (int u = 0; u < 8; ++u) {
            f4 o = vr * dKr[u];
            __builtin_nontemporal_store(o, &dV4[u * 64 + lane]);
        }
    }
}

// ===========================================================================
// bf16-path kernels
// ===========================================================================

// stage 0: convert W1, Wk, Wv (z=0..2) and z->bf16 (z=3)
__global__ __launch_bounds__(256) void wconv1(
    const float* __restrict__ W1, const float* __restrict__ Wk,
    const float* __restrict__ Wv, u16* __restrict__ W1t,
    u16* __restrict__ Wkt, u16* __restrict__ Wvt,
    const float* __restrict__ z, u16* __restrict__ zb)
{
    __shared__ u16 sm[64 * 66];
    int t = threadIdx.x;
    if (blockIdx.z == 3) {
        if (blockIdx.y != 0 || blockIdx.x >= 32) return;
        int i0 = blockIdx.x * 4096 + t * 16;
        u16 o[16];
#pragma unroll
        for (int q = 0; q < 4; ++q) {
            float4 f = *(const float4*)&z[i0 + q * 4];
            o[q*4+0] = f2b(f.x); o[q*4+1] = f2b(f.y);
            o[q*4+2] = f2b(f.z); o[q*4+3] = f2b(f.w);
        }
        *(bf16x8*)&zb[i0]     = *(bf16x8*)&o[0];
        *(bf16x8*)&zb[i0 + 8] = *(bf16x8*)&o[8];
        return;
    }
    const float* W = (blockIdx.z == 0) ? W1 : (blockIdx.z == 1) ? Wk : Wv;
    u16* T = (blockIdx.z == 0) ? W1t : (blockIdx.z == 1) ? Wkt : Wvt;
    wconv_tile(sm, W, T, blockIdx.x, blockIdx.y);
}

// stage 1 merged: [0,nG) gemm_h | [nG,2nG) gemm zWk | [2nG,3nG) gemm zWv |
//                 [3nG,3nG+1024) wconv W2 | [3nG+1024,3nG+2048) wconv Wq
__global__ __launch_bounds__(256) void mA(
    const u16* __restrict__ zb, const u16* __restrict__ W1t,
    const u16* __restrict__ Wkt, const u16* __restrict__ Wvt,
    float* __restrict__ ph, float* __restrict__ pk, float* __restrict__ pv,
    const float* __restrict__ W2, const float* __restrict__ Wq,
    u16* __restrict__ W2t, u16* __restrict__ Wqt, int kc, int nG)
{
    __shared__ u16 sm[64 * 66];
    int blk = blockIdx.x;
    if (blk < 3 * nG) {
        int sel = blk / nG;
        int r   = blk - sel * nG;
        const u16* Wt = (sel == 0) ? W1t : (sel == 1) ? Wkt : Wvt;
        float* pool   = (sel == 0) ? ph  : (sel == 1) ? pk  : pv;
        int nblk = r & 31, kblk = r >> 5;
        gemm_bf16_body(sm, zb, Wt, pool + (size_t)kblk * 64 * DD,
                       kc, nblk, kblk);
    } else {
        int r = blk - 3 * nG;           // 0..2047
        const float* W = (r < 1024) ? W2 : Wq;
        u16* T         = (r < 1024) ? W2t : Wqt;
        int rr = r & 1023;
        wconv_tile(sm, W, T, rr & 31, rr >> 5);
    }
}

// stage 2 merged epilogue: [0,512) ep_h | [512,1024) ep_kv
__global__ __launch_bounds__(256) void mEp(
    const float* __restrict__ ph, const float* __restrict__ pk,
    const float* __restrict__ pv, const float* __restrict__ b1,
    const float* __restrict__ bk, const float* __restrict__ bv,
    u16* __restrict__ hb, float* __restrict__ dKo, float* __restrict__ vo,
    int KS)
{
    int blk = blockIdx.x;
    if (blk < 512) {
        int i = blk * 256 + threadIdx.x;
        float s = b1[i & (DD - 1)];
        for (int ks = 0; ks < KS; ++ks) s += ph[(size_t)ks * BD + i];
        hb[i] = f2b(tanhf(s));
    } else {
        int i = (blk - 512) * 256 + threadIdx.x;
        int d = i & (DD - 1);
        float sk = 0.f, sv = 0.f;
        for (int ks = 0; ks < KS; ++ks) {
            sk += pk[(size_t)ks * BD + i];
            sv += pv[(size_t)ks * BD + i];
        }
        dKo[i] = expf(sk + bk[d]);
        vo[i]  = sv + bv[d];
    }
}

// stage 3 merged: [0,1024) dv_write b<32 | [1024,1024+nG) gemm_dz
__global__ __launch_bounds__(256) void mDZ(
    const float* __restrict__ v, const float* __restrict__ dK,
    float* __restrict__ dV, const u16* __restrict__ hb,
    const u16* __restrict__ W2t, float* __restrict__ p0, int kc, int nG)
{
    __shared__ u16 sm[4096];
    int blk = blockIdx.x;
    if (blk < 1024) {
        dv_body(v, dK, dV, blk >> 5, blk & 31);
    } else {
        int r = blk - 1024;
        int nblk = r & 31, kblk = r >> 5;
        gemm_bf16_body(sm, hb, W2t, p0 + (size_t)kblk * 64 * DD,
                       kc, nblk, kblk);
    }
}

__global__ __launch_bounds__(256) void ep_dz(
    const float* __restrict__ p, const float* __restrict__ b2,
    float* __restrict__ dz, u16* __restrict__ dzb, int KS)
{
    int i = blockIdx.x * 256 + threadIdx.x;
    float s = b2[i & (DD - 1)];
    for (int ks = 0; ks < KS; ++ks) s += p[(size_t)ks * BD + i];
    dz[i]  = s;
    dzb[i] = f2b(s);
}

// stage 4 merged: [0,1024) dv_write b>=32 | [1024,1024+2nG) gemm_q
__global__ __launch_bounds__(256) void mQ(
    const float* __restrict__ v, const float* __restrict__ dK,
    float* __restrict__ dV, const u16* __restrict__ zb,
    const u16* __restrict__ dzb, const u16* __restrict__ Wqt,
    float* __restrict__ pq, int kc, int nG)
{
    __shared__ u16 sm[4096];
    int blk = blockIdx.x;
    if (blk < 1024) {
        dv_body(v, dK, dV, 32 + (blk >> 5), blk & 31);
    } else {
        int r = blk - 1024;
        int zsel = (r >= nG) ? 1 : 0;
        int rr = r - zsel * nG;
        int nblk = rr & 31, kblk = rr >> 5;
        const u16* A = zsel ? dzb : zb;
        gemm_bf16_body(sm, A, Wqt,
                       pq + ((size_t)kblk * 128 + zsel * 64) * DD,
                       kc, nblk, kblk);
    }
}

__global__ __launch_bounds__(256) void ep_q_dq(
    const float* __restrict__ pq, const float* __restrict__ bq,
    float* __restrict__ qo, float* __restrict__ dqo, int KS)
{
    int i = blockIdx.x * 256 + threadIdx.x;
    int b = i >> 11, d = i & (DD - 1);
    float sq = 0.f, sd = 0.f;
    for (int ks = 0; ks < KS; ++ks) {
        const float* P = pq + (size_t)ks * (128 * DD);
        sq += P[(size_t)b * DD + d];
        sd += P[(size_t)(b + 64) * DD + d];
    }
    float bb = bq[d];
    float qv = expf(sq + bb);
    qo[i]  = qv;
    dqo[i] = qv * (sd + bb);
}

// ===========================================================================
// f32 fallback GEMM path (used only if d_ws is small)
// ===========================================================================
template<int MT>
__device__ __forceinline__ void gemm_body_f32(
    const float* __restrict__ A0, const float* __restrict__ A1,
    const float* __restrict__ W, float* __restrict__ part, int kc)
{
    constexpr int KC = 32;
    constexpr int RT = MT / 16;
    __shared__ float As[KC][MT];
    __shared__ float Ws[KC][64];

    const int t  = threadIdx.x;
    const int n0 = blockIdx.x * 64;
    const int k0 = blockIdx.y * kc;
    const int i  = t >> 4;
    const int j  = t & 15;

    float acc[RT][4];
#pragma unroll
    for (int r = 0; r < RT; ++r)
#pragma unroll
        for (int c = 0; c < 4; ++c) acc[r][c] = 0.f;

    for (int kk0 = 0; kk0 < kc; kk0 += KC) {
        {
            int kk = t >> 3;
            int nn = (t & 7) << 3;
            const float* s = W + (size_t)(k0 + kk0 + kk) * DD + n0 + nn;
            *(float4*)&Ws[kk][nn]     = *(const float4*)s;
            *(float4*)&Ws[kk][nn + 4] = *(const float4*)(s + 4);
        }
        if constexpr (MT == 64) {
            int m  = t & 63;
            int kb = (t >> 6) << 3;
            const float* s = A0 + (size_t)m * DD + k0 + kk0 + kb;
            float4 a0 = *(const float4*)s;
            float4 a1 = *(const float4*)(s + 4);
            As[kb+0][m] = a0.x; As[kb+1][m] = a0.y;
            As[kb+2][m] = a0.z; As[kb+3][m] = a0.w;
            As[kb+4][m] = a1.x; As[kb+5][m] = a1.y;
            As[kb+6][m] = a1.z; As[kb+7][m] = a1.w;
        } else {
            int m  = t & 127;
            int kb = (t >> 7) << 4;
            const float* base = (m < 64) ? (A0 + (size_t)m * DD)
                                         : (A1 + (size_t)(m - 64) * DD);
            const float* s = base + k0 + kk0 + kb;
#pragma unroll
            for (int p = 0; p < 4; ++p) {
                float4 av = *(const float4*)(s + p * 4);
                As[kb+p*4+0][m] = av.x; As[kb+p*4+1][m] = av.y;
                As[kb+p*4+2][m] = av.z; As[kb+p*4+3][m] = av.w;
            }
        }
        __syncthreads();
#pragma unroll
        for (int kk = 0; kk < KC; ++kk) {
            float4 wv = *(float4*)&Ws[kk][j << 2];
#pragma unroll
            for (int rq = 0; rq < RT / 4; ++rq) {
                float4 av = *(float4*)&As[kk][i * RT + rq * 4];
                acc[rq*4+0][0] = fmaf(av.x, wv.x, acc[rq*4+0][0]);
                acc[rq*4+0][1] = fmaf(av.x, wv.y, acc[rq*4+0][1]);
                acc[rq*4+0][2] = fmaf(av.x, wv.z, acc[rq*4+0][2]);
                acc[rq*4+0][3] = fmaf(av.x, wv.w, acc[rq*4+0][3]);
                acc[rq*4+1][0] = fmaf(av.y, wv.x, acc[rq*4+1][0]);
                acc[rq*4+1][1] = fmaf(av.y, wv.y, acc[rq*4+1][1]);
                acc[rq*4+1][2] = fmaf(av.y, wv.z, acc[rq*4+1][2]);
                acc[rq*4+1][3] = fmaf(av.y, wv.w, acc[rq*4+1][3]);
                acc[rq*4+2][0] = fmaf(av.z, wv.x, acc[rq*4+2][0]);
                acc[rq*4+2][1] = fmaf(av.z, wv.y, acc[rq*4+2][1]);
                acc[rq*4+2][2] = fmaf(av.z, wv.z, acc[rq*4+2][2]);
                acc[rq*4+2][3] = fmaf(av.z, wv.w, acc[rq*4+2][3]);
                acc[rq*4+3][0] = fmaf(av.w, wv.x, acc[rq*4+3][0]);
                acc[rq*4+3][1] = fmaf(av.w, wv.y, acc[rq*4+3][1]);
                acc[rq*4+3][2] = fmaf(av.w, wv.z, acc[rq*4+3][2]);
                acc[rq*4+3][3] = fmaf(av.w, wv.w, acc[rq*4+3][3]);
            }
        }
        __syncthreads();
    }

    float* P = part + (size_t)blockIdx.y * MT * DD + n0 + (j << 2);
#pragma unroll
    for (int r = 0; r < RT; ++r)
        *(float4*)&P[(size_t)(i * RT + r) * DD] =
            make_float4(acc[r][0], acc[r][1], acc[r][2], acc[r][3]);
}

__global__ __launch_bounds__(256) void gemm64(
    const float* __restrict__ A, const float* __restrict__ W,
    float* __restrict__ part, int kc)
{ gemm_body_f32<64>(A, A, W, part, kc); }

__global__ __launch_bounds__(256) void gemm64_z2(
    const float* __restrict__ A,
    const float* __restrict__ W0, const float* __restrict__ W1,
    float* __restrict__ p0, float* __restrict__ p1, int kc)
{
    const float* W = blockIdx.z ? W1 : W0;
    float*       P = blockIdx.z ? p1 : p0;
    gemm_body_f32<64>(A, A, W, P, kc);
}

__global__ __launch_bounds__(256) void gemm128(
    const float* __restrict__ A0, const float* __restrict__ A1,
    const float* __restrict__ W, float* __restrict__ part, int kc)
{ gemm_body_f32<128>(A0, A1, W, part, kc); }

__global__ __launch_bounds__(256) void epilogue_f32(
    const float* __restrict__ part, const float* __restrict__ bias,
    float* __restrict__ out, int act, int KS)
{
    int i = blockIdx.x * 256 + threadIdx.x;
    float s = bias[i & (DD - 1)];
    for (int ks = 0; ks < KS; ++ks) s += part[(size_t)ks * BD + i];
    if (act == 1) s = tanhf(s);
    out[i] = s;
}

__global__ __launch_bounds__(256) void ep_kv_f32(
    const float* __restrict__ pk, const float* __restrict__ pv,
    const float* __restrict__ bk, const float* __restrict__ bv,
    float* __restrict__ dKo, float* __restrict__ vo, int KS)
{
    int i = blockIdx.x * 256 + threadIdx.x;
    int d = i & (DD - 1);
    float sk = 0.f, sv = 0.f;
    for (int ks = 0; ks < KS; ++ks) {
        sk += pk[(size_t)ks * BD + i];
        sv += pv[(size_t)ks * BD + i];
    }
    dKo[i] = expf(sk + bk[d]);
    vo[i]  = sv + bv[d];
}

__global__ __launch_bounds__(256) void dv_write_full(
    const float* __restrict__ v, const float* __restrict__ dK,
    float* __restrict__ dV)
{
    dv_body(v, dK, dV, blockIdx.x >> 5, blockIdx.x & 31);
}

// ===========================================================================
// shared tail kernels
// ===========================================================================
__global__ __launch_bounds__(256) void reduce_a_da(
    const float* __restrict__ q, const float* __restrict__ dK,
    const float* __restrict__ dq, const float* __restrict__ Kin,
    float* __restrict__ a_ws, float* __restrict__ da_out)
{
    int b = blockIdx.x;
    int t = threadIdx.x;
    const float* qb  = q   + (size_t)b * DD;
    const float* dKb = dK  + (size_t)b * DD;
    const float* dqb = dq  + (size_t)b * DD;
    const float* Kb  = Kin + (size_t)b * DD;

    float s1 = 0.f, s2 = 0.f;
    for (int i = t; i < DD; i += 256) {
        s1 = fmaf(qb[i],  dKb[i], s1);
        s2 = fmaf(dqb[i], Kb[i],  s2);
    }
#pragma unroll
    for (int off = 32; off; off >>= 1) {
        s1 += __shfl_down(s1, off);
        s2 += __shfl_down(s2, off);
    }
    __shared__ float r1[4], r2[4];
    if ((t & 63) == 0) { r1[t >> 6] = s1; r2[t >> 6] = s2; }
    __syncthreads();
    if (t == 0) {
        float a  = r1[0] + r1[1] + r1[2] + r1[3];
        float k2 = r2[0] + r2[1] + r2[2] + r2[3];
        a_ws[b]   = a;
        da_out[b] = a + k2;
    }
}

// pure read stream: dc[b,d] = v[b,d]*a[b] + sum_e V[b,d,e]*dq[b,e]
__global__ __launch_bounds__(256) void dc_dot(
    const float* __restrict__ V, const float* __restrict__ v,
    const float* __restrict__ dq, const float* __restrict__ a,
    float* __restrict__ dc)
{
    int b     = blockIdx.x >> 5;
    int chunk = blockIdx.x & 31;
    int wave  = threadIdx.x >> 6;
    int lane  = threadIdx.x & 63;

    const f4* dq4 = (const f4*)(dq + ((size_t)b << 11));
    f4 dqr[8];
#pragma unroll
    for (int u = 0; u < 8; ++u) dqr[u] = dq4[u * 64 + lane];
    float ab = a[b];

    int row0 = chunk * 64 + wave * 16;
    for (int g = 0; g < 4; ++g) {
        float dot[4];
#pragma unroll
        for (int r2 = 0; r2 < 4; ++r2) {
            int row = row0 + g * 4 + r2;
            const f4* V4 = (const f4*)(V + (((size_t)((b << 11) | row)) << 11));
            float d = 0.f;
#pragma unroll
            for (int u = 0; u < 8; ++u) {
                f4 Vv = __builtin_nontemporal_load(&V4[u * 64 + lane]);
                d += Vv[0] * dqr[u][0] + Vv[1] * dqr[u][1]
                   + Vv[2] * dqr[u][2] + Vv[3] * dqr[u][3];
            }
            dot[r2] = d;
        }
#pragma unroll
        for (int r2 = 0; r2 < 4; ++r2) {
            float d = dot[r2];
#pragma unroll
            for (int s = 32; s; s >>= 1) d += __shfl_down(d, s);
            if (lane == 0) {
                int row = row0 + g * 4 + r2;
                dc[((size_t)b << 11) + row] =
                    v[((size_t)b << 11) + row] * ab + d;
            }
        }
    }
}

// ===========================================================================
extern "C" void kernel_launch(void* const* d_in, const int* in_sizes, int n_in,
                              void* d_out, int out_size, void* d_ws, size_t ws_size,
                              hipStream_t stream)
{
    const float* z   = (const float*)d_in[1];
    const float* Kin = (const float*)d_in[2];
    const float* Vin = (const float*)d_in[3];
    const float* Wq  = (const float*)d_in[4];
    const float* bq  = (const float*)d_in[5];
    const float* Wk  = (const float*)d_in[6];
    const float* bk  = (const float*)d_in[7];
    const float* Wv  = (const float*)d_in[8];
    const float* bv  = (const float*)d_in[9];
    const float* W1  = (const float*)d_in[10];
    const float* b1  = (const float*)d_in[11];
    const float* W2  = (const float*)d_in[12];
    const float* b2  = (const float*)d_in[13];

    float* out   = (float*)d_out;
    float* o_dz  = out;
    float* o_da  = out + BD;
    float* o_dc  = out + BD + BB;
    float* o_dK  = out + 2 * BD + BB;
    float* o_dV  = out + 3 * BD + BB;

    float* ws    = (float*)d_ws;
    float* ws_v  = ws;
    float* ws_q  = ws + BD;
    float* ws_dq = ws + 2 * BD;
    float* ws_a  = ws + 3 * BD;          // 64
    float* ws_h  = ws + 3 * BD + 64;     // fallback only
    u16*   zb    = (u16*)(ws + 4 * BD + 64);
    u16*   hb    = zb + BD;
    u16*   dzb   = hb + BD;
    u16*   wt    = dzb + BD;             // 5 * WN u16
    float* poolb = (float*)(wt + 5ull * WN);

    const size_t pre_fl = 4ull * BD + 64 + (3ull * BD + 5ull * WN) / 2;

    // bf16 path needs 3 concurrent partial buffers (h, k, v) of KS*BD each
    int KS = 0;
    for (int ks = 16; ks >= 4; ks >>= 1)
        if ((pre_fl + 3ull * ks * BD) * 4ull <= ws_size) { KS = ks; break; }

    dim3 blk(256);
    dim3 gE(BD / 256);

    if (KS) {
        // ------------------- bf16 MFMA path, merged dispatches -------------
        int kc = DD / KS;
        int nG = 32 * KS;                 // blocks per 64-row GEMM
        float* ph = poolb;
        float* pk = poolb + (size_t)KS * BD;
        float* pv = poolb + 2ull * KS * BD;
        float* p0 = poolb;                // reused after mEp
        float* pq = poolb;                // [KS][128][DD], reused after ep_dz

        u16* W1t = wt;
        u16* W2t = wt + 1ull * WN;
        u16* Wkt = wt + 2ull * WN;
        u16* Wvt = wt + 3ull * WN;
        u16* Wqt = wt + 4ull * WN;

        // 0) convert W1, Wk, Wv, z
        wconv1<<<dim3(32, 32, 4), blk, 0, stream>>>(
            W1, Wk, Wv, W1t, Wkt, Wvt, z, zb);

        // 1) gemm_h ∥ gemm_kv ∥ wconv(W2, Wq)
        mA<<<dim3(3 * nG + 2048), blk, 0, stream>>>(
            zb, W1t, Wkt, Wvt, ph, pk, pv, W2, Wq, W2t, Wqt, kc, nG);

        // 2) ep_h ∥ ep_kv
        mEp<<<dim3(1024), blk, 0, stream>>>(
            ph, pk, pv, b1, bk, bv, hb, o_dK, ws_v, KS);

        // 3) dv_write (b<32) ∥ gemm_dz
        mDZ<<<dim3(1024 + nG), blk, 0, stream>>>(
            ws_v, o_dK, o_dV, hb, W2t, p0, kc, nG);

        ep_dz<<<gE, blk, 0, stream>>>(p0, b2, o_dz, dzb, KS);

        // 4) dv_write (b>=32) ∥ gemm_q
        mQ<<<dim3(1024 + 2 * nG), blk, 0, stream>>>(
            ws_v, o_dK, o_dV, zb, dzb, Wqt, pq, kc, nG);

        ep_q_dq<<<gE, blk, 0, stream>>>(pq, bq, ws_q, ws_dq, KS);
    } else {
        // ------------------- f32 fallback path -------------------
        float* pool = ws + 4 * BD + 64;
        int KSf = 16;
        while (KSf > 1 &&
               ((size_t)(4 * BD + 64) + 2ull * KSf * BD) * 4ull > ws_size)
            KSf >>= 1;
        int kc = DD / KSf;
        float* p0 = pool;
        float* p1 = pool + (size_t)KSf * BD;

        dim3 gG(DD / 64, KSf);
        dim3 gG2(DD / 64, KSf, 2);

        gemm64<<<gG, blk, 0, stream>>>(z, W1, p0, kc);
        epilogue_f32<<<gE, blk, 0, stream>>>(p0, b1, ws_h, 1, KSf);

        gemm64<<<gG, blk, 0, stream>>>(ws_h, W2, p0, kc);
        epilogue_f32<<<gE, blk, 0, stream>>>(p0, b2, o_dz, 0, KSf);

        gemm64_z2<<<gG2, blk, 0, stream>>>(z, Wk, Wv, p0, p1, kc);
        ep_kv_f32<<<gE, blk, 0, stream>>>(p0, p1, bk, bv, o_dK, ws_v, KSf);

        dv_write_full<<<dim3(BB * 32), blk, 0, stream>>>(ws_v, o_dK, o_dV);

        gemm128<<<gG, blk, 0, stream>>>(z, o_dz, Wq, p0, kc);
        ep_q_dq<<<gE, blk, 0, stream>>>(p0, bq, ws_q, ws_dq, KSf);
    }

    // 5) a = q . dK ; da = a + dq . K
    reduce_a_da<<<dim3(BB), blk, 0, stream>>>(ws_q, o_dK, ws_dq, Kin, ws_a, o_da);

    // 6) dc = v*a + V @ dq  — pure read stream
    dc_dot<<<dim3(BB * 32), blk, 0, stream>>>(Vin, ws_v, ws_dq, ws_a, o_dc);
}

// Round 7
// 411.671 us; speedup vs baseline: 1.2962x; 1.0338x over previous
//
#include <hip/hip_runtime.h>
#include <cstddef>
#include <math.h>

#define BB 64
#define DD 2048
#define HH 2048
#define BD (BB*DD)   // 131072
#define WN (2048*2048)

typedef unsigned short u16;
typedef __attribute__((ext_vector_type(8))) short bf16x8;
typedef __attribute__((ext_vector_type(4))) float f32x4;
typedef __attribute__((ext_vector_type(4))) float f4;

__device__ __forceinline__ u16 f2b(float x) {
    union { float f; unsigned u; } v; v.f = x;
    unsigned r = v.u + 0x7FFFu + ((v.u >> 16) & 1u);
    return (u16)(r >> 16);
}

__device__ __forceinline__ void gload16(const void* g, void* l) {
    __builtin_amdgcn_global_load_lds(
        (__attribute__((address_space(1))) void*)g,
        (__attribute__((address_space(3))) void*)l, 16, 0, 0);
}

// ===========================================================================
// shared device bodies
// ===========================================================================

// weight tile f32[k][n] -> bf16 T[n][k]; sm >= 64*66 u16
__device__ __forceinline__ void wconv_tile(
    u16* sm, const float* __restrict__ W, u16* __restrict__ T,
    int kb, int nb)
{
    int t = threadIdx.x;
    int k0 = kb * 64, n0 = nb * 64;
    {
        int r = t >> 2, c0 = (t & 3) * 16;
        const float* src = W + (size_t)(k0 + r) * DD + n0 + c0;
#pragma unroll
        for (int q = 0; q < 4; ++q) {
            float4 f = *(const float4*)(src + q * 4);
            sm[r * 66 + c0 + q*4 + 0] = f2b(f.x);
            sm[r * 66 + c0 + q*4 + 1] = f2b(f.y);
            sm[r * 66 + c0 + q*4 + 2] = f2b(f.z);
            sm[r * 66 + c0 + q*4 + 3] = f2b(f.w);
        }
    }
    __syncthreads();
    {
        int rn = t >> 2, ck = (t & 3) * 16;
        u16 o[16];
#pragma unroll
        for (int j = 0; j < 16; ++j) o[j] = sm[(ck + j) * 66 + rn];
        u16* dst = T + (size_t)(n0 + rn) * DD + k0 + ck;
        *(bf16x8*)dst       = *(bf16x8*)&o[0];
        *(bf16x8*)(dst + 8) = *(bf16x8*)&o[8];
    }
}

// ---- full-K (K=2048) 64x64 MFMA GEMM, 3-buffer 2-ahead pipeline.
// NS = # A-streams (1 or 2). sm: 3 * (NS+1) * 2048 u16.
// Counted vmcnt + raw s_barrier: prefetch stays in flight across barriers.
template<int NS>
__device__ __forceinline__ void gemm_fullk(
    u16* sm, const u16* __restrict__ A0, const u16* __restrict__ A1,
    const u16* __restrict__ Wt, int nblk, f32x4* acc0, f32x4* acc1)
{
    constexpr int NS1 = NS + 1;
    constexpr int REG = NS1 * 2048;      // u16 per buffer
    const int t = threadIdx.x, w = t >> 6, lane = t & 63;
    const int n0 = nblk * 64;
    const int srow = lane >> 2;          // 0..15
    const int sk   = (lane & 3) * 8;     // u16 offset, 16B chunks

    const u16* gA0 = A0 + (size_t)(w * 16 + srow) * DD + sk;
    const u16* gA1 = (NS == 2) ? A1 + (size_t)(w * 16 + srow) * DD + sk : A0;
    const u16* gW  = Wt + (size_t)(n0 + w * 16 + srow) * DD + sk;
    const int woff = w * 512;

    const int lane15 = lane & 15;
    const int k8 = (lane >> 4) * 8;

    auto stage = [&](int it, int buf) {
        u16* base = sm + buf * REG;
        gload16(gA0 + it * 32, base + woff);
        if constexpr (NS == 2) gload16(gA1 + it * 32, base + 2048 + woff);
        gload16(gW + it * 32, base + (NS1 - 1) * 2048 + woff);
    };

    constexpr int nt = DD / 32;          // 64
    stage(0, 0);
    stage(1, 1);
    for (int it = 0; it < nt; ++it) {
        const int cur = it % 3;
        if (it + 2 < nt) {
            stage(it + 2, (it + 2) % 3);
            if constexpr (NS == 1) asm volatile("s_waitcnt vmcnt(4)" ::: "memory");
            else                   asm volatile("s_waitcnt vmcnt(6)" ::: "memory");
        } else if (it + 1 < nt) {
            if constexpr (NS == 1) asm volatile("s_waitcnt vmcnt(2)" ::: "memory");
            else                   asm volatile("s_waitcnt vmcnt(3)" ::: "memory");
        } else {
            asm volatile("s_waitcnt vmcnt(0)" ::: "memory");
        }
        __builtin_amdgcn_s_barrier();

        const u16* base = sm + cur * REG;
        bf16x8 bfrag = *(const bf16x8*)&base[(NS1-1)*2048 + (w*16 + lane15)*32 + k8];
#pragma unroll
        for (int mt = 0; mt < 4; ++mt) {
            bf16x8 a0 = *(const bf16x8*)&base[(mt*16 + lane15)*32 + k8];
            acc0[mt] = __builtin_amdgcn_mfma_f32_16x16x32_bf16(a0, bfrag, acc0[mt], 0, 0, 0);
        }
        if constexpr (NS == 2) {
#pragma unroll
            for (int mt = 0; mt < 4; ++mt) {
                bf16x8 a1 = *(const bf16x8*)&base[2048 + (mt*16 + lane15)*32 + k8];
                acc1[mt] = __builtin_amdgcn_mfma_f32_16x16x32_bf16(a1, bfrag, acc1[mt], 0, 0, 0);
            }
        }
        __builtin_amdgcn_s_barrier();
    }
}

// ---- dV row-chunk writer: dV[b, chunk*64 .. +64, :] = v ⊗ dK (nt stores)
__device__ __forceinline__ void dv_body(
    const float* __restrict__ v, const float* __restrict__ dK,
    float* __restrict__ dV, int b, int chunk)
{
    int wave = threadIdx.x >> 6;
    int lane = threadIdx.x & 63;

    const f4* dK4 = (const f4*)(dK + ((size_t)b << 11));
    f4 dKr[8];
#pragma unroll
    for (int u = 0; u < 8; ++u) dKr[u] = dK4[u * 64 + lane];

    int row0 = chunk * 64 + wave * 16;
    for (int rr = 0; rr < 16; ++rr) {
        int row = row0 + rr;
        float vr = v[((size_t)b << 11) + row];
        f4* dV4 = (f4*)(dV + (((size_t)((b << 11) | row)) << 11));
#pragma unroll
        for (int u = 0; u < 8; ++u) {
            f4 o = vr * dKr[u];
            __builtin_nontemporal_store(o, &dV4[u * 64 + lane]);
        }
    }
}

// ===========================================================================
// bf16-path kernels
// ===========================================================================

// k_pre: convert W1, Wk, Wv (z=0..2) and z->bf16 (z=3)
__global__ __launch_bounds__(256) void wconv1(
    const float* __restrict__ W1, const float* __restrict__ Wk,
    const float* __restrict__ Wv, u16* __restrict__ W1t,
    u16* __restrict__ Wkt, u16* __restrict__ Wvt,
    const float* __restrict__ z, u16* __restrict__ zb)
{
    __shared__ u16 sm[64 * 66];
    int t = threadIdx.x;
    if (blockIdx.z == 3) {
        if (blockIdx.y != 0 || blockIdx.x >= 32) return;
        int i0 = blockIdx.x * 4096 + t * 16;
        u16 o[16];
#pragma unroll
        for (int q = 0; q < 4; ++q) {
            float4 f = *(const float4*)&z[i0 + q * 4];
            o[q*4+0] = f2b(f.x); o[q*4+1] = f2b(f.y);
            o[q*4+2] = f2b(f.z); o[q*4+3] = f2b(f.w);
        }
        *(bf16x8*)&zb[i0]     = *(bf16x8*)&o[0];
        *(bf16x8*)&zb[i0 + 8] = *(bf16x8*)&o[8];
        return;
    }
    const float* W = (blockIdx.z == 0) ? W1 : (blockIdx.z == 1) ? Wk : Wv;
    u16* T = (blockIdx.z == 0) ? W1t : (blockIdx.z == 1) ? Wkt : Wvt;
    wconv_tile(sm, W, T, blockIdx.x, blockIdx.y);
}

// mA: [0,32) gemm_h | [32,64) gemm_k | [64,96) gemm_v | [96,2144) wconv W2,Wq
__global__ __launch_bounds__(256) void mA(
    const u16* __restrict__ zb, const u16* __restrict__ W1t,
    const u16* __restrict__ Wkt, const u16* __restrict__ Wvt,
    const float* __restrict__ b1, const float* __restrict__ bk,
    const float* __restrict__ bv, u16* __restrict__ hb,
    float* __restrict__ dKo, float* __restrict__ vo,
    const float* __restrict__ W2, const float* __restrict__ Wq,
    u16* __restrict__ W2t, u16* __restrict__ Wqt)
{
    __shared__ u16 sm[3 * 4096];         // 24 KB
    int blk = blockIdx.x;
    if (blk < 96) {
        int sel  = blk >> 5;
        int nblk = blk & 31;
        const u16* Wt = (sel == 0) ? W1t : (sel == 1) ? Wkt : Wvt;
        f32x4 acc[4];
#pragma unroll
        for (int mt = 0; mt < 4; ++mt) acc[mt] = (f32x4){0.f,0.f,0.f,0.f};
        gemm_fullk<1>(sm, zb, zb, Wt, nblk, acc, nullptr);

        int w = threadIdx.x >> 6, lane = threadIdx.x & 63;
        int col = nblk * 64 + w * 16 + (lane & 15);
        int r4  = (lane >> 4) * 4;
        if (sel == 0) {
            float bb = b1[col];
#pragma unroll
            for (int mt = 0; mt < 4; ++mt)
#pragma unroll
                for (int j = 0; j < 4; ++j)
                    hb[(size_t)(mt*16 + r4 + j) * DD + col] =
                        f2b(tanhf(acc[mt][j] + bb));
        } else if (sel == 1) {
            float bb = bk[col];
#pragma unroll
            for (int mt = 0; mt < 4; ++mt)
#pragma unroll
                for (int j = 0; j < 4; ++j)
                    dKo[(size_t)(mt*16 + r4 + j) * DD + col] =
                        expf(acc[mt][j] + bb);
        } else {
            float bb = bv[col];
#pragma unroll
            for (int mt = 0; mt < 4; ++mt)
#pragma unroll
                for (int j = 0; j < 4; ++j)
                    vo[(size_t)(mt*16 + r4 + j) * DD + col] =
                        acc[mt][j] + bb;
        }
    } else {
        int r = blk - 96;                // 0..2047
        const float* W = (r < 1024) ? W2 : Wq;
        u16* T         = (r < 1024) ? W2t : Wqt;
        int rr = r & 1023;
        wconv_tile(sm, W, T, rr & 31, rr >> 5);
    }
}

// mDZ: [0,32) gemm_dz (full-K, writes dz f32 + dzb bf16) | [32,1056) dv b<32
__global__ __launch_bounds__(256) void mDZ(
    const u16* __restrict__ hb, const u16* __restrict__ W2t,
    const float* __restrict__ b2, float* __restrict__ dz,
    u16* __restrict__ dzb,
    const float* __restrict__ v, const float* __restrict__ dK,
    float* __restrict__ dV)
{
    __shared__ u16 sm[3 * 4096];         // 24 KB
    int blk = blockIdx.x;
    if (blk < 32) {
        f32x4 acc[4];
#pragma unroll
        for (int mt = 0; mt < 4; ++mt) acc[mt] = (f32x4){0.f,0.f,0.f,0.f};
        gemm_fullk<1>(sm, hb, hb, W2t, blk, acc, nullptr);

        int w = threadIdx.x >> 6, lane = threadIdx.x & 63;
        int col = blk * 64 + w * 16 + (lane & 15);
        int r4  = (lane >> 4) * 4;
        float bb = b2[col];
#pragma unroll
        for (int mt = 0; mt < 4; ++mt)
#pragma unroll
            for (int j = 0; j < 4; ++j) {
                float s = acc[mt][j] + bb;
                size_t idx = (size_t)(mt*16 + r4 + j) * DD + col;
                dz[idx]  = s;
                dzb[idx] = f2b(s);
            }
    } else {
        int r = blk - 32;
        dv_body(v, dK, dV, r >> 5, r & 31);
    }
}

// mQ: [0,32) dual gemm_q (z@Wq and dz@Wq share B-frag) | [32,1056) dv b>=32
__global__ __launch_bounds__(256) void mQ(
    const u16* __restrict__ zb, const u16* __restrict__ dzb,
    const u16* __restrict__ Wqt, const float* __restrict__ bq,
    float* __restrict__ qo, float* __restrict__ dqo,
    const float* __restrict__ v, const float* __restrict__ dK,
    float* __restrict__ dV)
{
    __shared__ u16 sm[3 * 6144];         // 36 KB
    int blk = blockIdx.x;
    if (blk < 32) {
        f32x4 az[4], ad[4];
#pragma unroll
        for (int mt = 0; mt < 4; ++mt) {
            az[mt] = (f32x4){0.f,0.f,0.f,0.f};
            ad[mt] = (f32x4){0.f,0.f,0.f,0.f};
        }
        gemm_fullk<2>(sm, zb, dzb, Wqt, blk, az, ad);

        int w = threadIdx.x >> 6, lane = threadIdx.x & 63;
        int col = blk * 64 + w * 16 + (lane & 15);
        int r4  = (lane >> 4) * 4;
        float bb = bq[col];
#pragma unroll
        for (int mt = 0; mt < 4; ++mt)
#pragma unroll
            for (int j = 0; j < 4; ++j) {
                float qv = expf(az[mt][j] + bb);
                size_t idx = (size_t)(mt*16 + r4 + j) * DD + col;
                qo[idx]  = qv;
                dqo[idx] = qv * (ad[mt][j] + bb);
            }
    } else {
        int r = blk - 32;
        dv_body(v, dK, dV, 32 + (r >> 5), r & 31);
    }
}

// dc_fin: per-block recompute a[b] = q·dK (L2-hot rows); chunk0 writes da;
// then the pure nt-read V stream: dc = v*a + V@dq
__global__ __launch_bounds__(256) void dc_fin(
    const float* __restrict__ V, const float* __restrict__ v,
    const float* __restrict__ q, const float* __restrict__ dK,
    const float* __restrict__ dq, const float* __restrict__ Kin,
    float* __restrict__ da, float* __restrict__ dc)
{
    int b     = blockIdx.x >> 5;
    int chunk = blockIdx.x & 31;
    int t     = threadIdx.x;
    int wave  = t >> 6, lane = t & 63;

    const float* qb  = q   + (size_t)b * DD;
    const float* dKb = dK  + (size_t)b * DD;
    const float* dqb = dq  + (size_t)b * DD;
    const float* Kb  = Kin + (size_t)b * DD;

    float s1 = 0.f, s2 = 0.f;
    for (int i = t; i < DD; i += 256) {
        s1 = fmaf(qb[i],  dKb[i], s1);
        s2 = fmaf(dqb[i], Kb[i],  s2);
    }
#pragma unroll
    for (int off = 32; off; off >>= 1) {
        s1 += __shfl_down(s1, off);
        s2 += __shfl_down(s2, off);
    }
    __shared__ float r1[4], r2[4], sa;
    if ((t & 63) == 0) { r1[t >> 6] = s1; r2[t >> 6] = s2; }
    __syncthreads();
    if (t == 0) {
        float a = r1[0] + r1[1] + r1[2] + r1[3];
        sa = a;
        if (chunk == 0) da[b] = a + r2[0] + r2[1] + r2[2] + r2[3];
    }
    __syncthreads();
    float ab = sa;

    const f4* dq4 = (const f4*)(dq + ((size_t)b << 11));
    f4 dqr[8];
#pragma unroll
    for (int u = 0; u < 8; ++u) dqr[u] = dq4[u * 64 + lane];

    int row0 = chunk * 64 + wave * 16;
    for (int g = 0; g < 4; ++g) {
        float dot[4];
#pragma unroll
        for (int r2i = 0; r2i < 4; ++r2i) {
            int row = row0 + g * 4 + r2i;
            const f4* V4 = (const f4*)(V + (((size_t)((b << 11) | row)) << 11));
            float d = 0.f;
#pragma unroll
            for (int u = 0; u < 8; ++u) {
                f4 Vv = __builtin_nontemporal_load(&V4[u * 64 + lane]);
                d += Vv[0] * dqr[u][0] + Vv[1] * dqr[u][1]
                   + Vv[2] * dqr[u][2] + Vv[3] * dqr[u][3];
            }
            dot[r2i] = d;
        }
#pragma unroll
        for (int r2i = 0; r2i < 4; ++r2i) {
            float d = dot[r2i];
#pragma unroll
            for (int s = 32; s; s >>= 1) d += __shfl_down(d, s);
            if (lane == 0) {
                int row = row0 + g * 4 + r2i;
                dc[((size_t)b << 11) + row] =
                    v[((size_t)b << 11) + row] * ab + d;
            }
        }
    }
}

// ===========================================================================
// f32 fallback GEMM path (used only if d_ws is small)
// ===========================================================================
template<int MT>
__device__ __forceinline__ void gemm_body_f32(
    const float* __restrict__ A0, const float* __restrict__ A1,
    const float* __restrict__ W, float* __restrict__ part, int kc)
{
    constexpr int KC = 32;
    constexpr int RT = MT / 16;
    __shared__ float As[KC][MT];
    __shared__ float Ws[KC][64];

    const int t  = threadIdx.x;
    const int n0 = blockIdx.x * 64;
    const int k0 = blockIdx.y * kc;
    const int i  = t >> 4;
    const int j  = t & 15;

    float acc[RT][4];
#pragma unroll
    for (int r = 0; r < RT; ++r)
#pragma unroll
        for (int c = 0; c < 4; ++c) acc[r][c] = 0.f;

    for (int kk0 = 0; kk0 < kc; kk0 += KC) {
        {
            int kk = t >> 3;
            int nn = (t & 7) << 3;
            const float* s = W + (size_t)(k0 + kk0 + kk) * DD + n0 + nn;
            *(float4*)&Ws[kk][nn]     = *(const float4*)s;
            *(float4*)&Ws[kk][nn + 4] = *(const float4*)(s + 4);
        }
        if constexpr (MT == 64) {
            int m  = t & 63;
            int kb = (t >> 6) << 3;
            const float* s = A0 + (size_t)m * DD + k0 + kk0 + kb;
            float4 a0 = *(const float4*)s;
            float4 a1 = *(const float4*)(s + 4);
            As[kb+0][m] = a0.x; As[kb+1][m] = a0.y;
            As[kb+2][m] = a0.z; As[kb+3][m] = a0.w;
            As[kb+4][m] = a1.x; As[kb+5][m] = a1.y;
            As[kb+6][m] = a1.z; As[kb+7][m] = a1.w;
        } else {
            int m  = t & 127;
            int kb = (t >> 7) << 4;
            const float* base = (m < 64) ? (A0 + (size_t)m * DD)
                                         : (A1 + (size_t)(m - 64) * DD);
            const float* s = base + k0 + kk0 + kb;
#pragma unroll
            for (int p = 0; p < 4; ++p) {
                float4 av = *(const float4*)(s + p * 4);
                As[kb+p*4+0][m] = av.x; As[kb+p*4+1][m] = av.y;
                As[kb+p*4+2][m] = av.z; As[kb+p*4+3][m] = av.w;
            }
        }
        __syncthreads();
#pragma unroll
        for (int kk = 0; kk < KC; ++kk) {
            float4 wv = *(float4*)&Ws[kk][j << 2];
#pragma unroll
            for (int rq = 0; rq < RT / 4; ++rq) {
                float4 av = *(float4*)&As[kk][i * RT + rq * 4];
                acc[rq*4+0][0] = fmaf(av.x, wv.x, acc[rq*4+0][0]);
                acc[rq*4+0][1] = fmaf(av.x, wv.y, acc[rq*4+0][1]);
                acc[rq*4+0][2] = fmaf(av.x, wv.z, acc[rq*4+0][2]);
                acc[rq*4+0][3] = fmaf(av.x, wv.w, acc[rq*4+0][3]);
                acc[rq*4+1][0] = fmaf(av.y, wv.x, acc[rq*4+1][0]);
                acc[rq*4+1][1] = fmaf(av.y, wv.y, acc[rq*4+1][1]);
                acc[rq*4+1][2] = fmaf(av.y, wv.z, acc[rq*4+1][2]);
                acc[rq*4+1][3] = fmaf(av.y, wv.w, acc[rq*4+1][3]);
                acc[rq*4+2][0] = fmaf(av.z, wv.x, acc[rq*4+2][0]);
                acc[rq*4+2][1] = fmaf(av.z, wv.y, acc[rq*4+2][1]);
                acc[rq*4+2][2] = fmaf(av.z, wv.z, acc[rq*4+2][2]);
                acc[rq*4+2][3] = fmaf(av.z, wv.w, acc[rq*4+2][3]);
                acc[rq*4+3][0] = fmaf(av.w, wv.x, acc[rq*4+3][0]);
                acc[rq*4+3][1] = fmaf(av.w, wv.y, acc[rq*4+3][1]);
                acc[rq*4+3][2] = fmaf(av.w, wv.z, acc[rq*4+3][2]);
                acc[rq*4+3][3] = fmaf(av.w, wv.w, acc[rq*4+3][3]);
            }
        }
        __syncthreads();
    }

    float* P = part + (size_t)blockIdx.y * MT * DD + n0 + (j << 2);
#pragma unroll
    for (int r = 0; r < RT; ++r)
        *(float4*)&P[(size_t)(i * RT + r) * DD] =
            make_float4(acc[r][0], acc[r][1], acc[r][2], acc[r][3]);
}

__global__ __launch_bounds__(256) void gemm64(
    const float* __restrict__ A, const float* __restrict__ W,
    float* __restrict__ part, int kc)
{ gemm_body_f32<64>(A, A, W, part, kc); }

__global__ __launch_bounds__(256) void gemm64_z2(
    const float* __restrict__ A,
    const float* __restrict__ W0, const float* __restrict__ W1,
    float* __restrict__ p0, float* __restrict__ p1, int kc)
{
    const float* W = blockIdx.z ? W1 : W0;
    float*       P = blockIdx.z ? p1 : p0;
    gemm_body_f32<64>(A, A, W, P, kc);
}

__global__ __launch_bounds__(256) void gemm128(
    const float* __restrict__ A0, const float* __restrict__ A1,
    const float* __restrict__ W, float* __restrict__ part, int kc)
{ gemm_body_f32<128>(A0, A1, W, part, kc); }

__global__ __launch_bounds__(256) void epilogue_f32(
    const float* __restrict__ part, const float* __restrict__ bias,
    float* __restrict__ out, int act, int KS)
{
    int i = blockIdx.x * 256 + threadIdx.x;
    float s = bias[i & (DD - 1)];
    for (int ks = 0; ks < KS; ++ks) s += part[(size_t)ks * BD + i];
    if (act == 1) s = tanhf(s);
    out[i] = s;
}

__global__ __launch_bounds__(256) void ep_kv_f32(
    const float* __restrict__ pk, const float* __restrict__ pv,
    const float* __restrict__ bk, const float* __restrict__ bv,
    float* __restrict__ dKo, float* __restrict__ vo, int KS)
{
    int i = blockIdx.x * 256 + threadIdx.x;
    int d = i & (DD - 1);
    float sk = 0.f, sv = 0.f;
    for (int ks = 0; ks < KS; ++ks) {
        sk += pk[(size_t)ks * BD + i];
        sv += pv[(size_t)ks * BD + i];
    }
    dKo[i] = expf(sk + bk[d]);
    vo[i]  = sv + bv[d];
}

__global__ __launch_bounds__(256) void ep_q_dq_f32(
    const float* __restrict__ pq, const float* __restrict__ bq,
    float* __restrict__ qo, float* __restrict__ dqo, int KS)
{
    int i = blockIdx.x * 256 + threadIdx.x;
    int b = i >> 11, d = i & (DD - 1);
    float sq = 0.f, sd = 0.f;
    for (int ks = 0; ks < KS; ++ks) {
        const float* P = pq + (size_t)ks * (128 * DD);
        sq += P[(size_t)b * DD + d];
        sd += P[(size_t)(b + 64) * DD + d];
    }
    float bb = bq[d];
    float qv = expf(sq + bb);
    qo[i]  = qv;
    dqo[i] = qv * (sd + bb);
}

__global__ __launch_bounds__(256) void dv_write_full(
    const float* __restrict__ v, const float* __restrict__ dK,
    float* __restrict__ dV)
{
    dv_body(v, dK, dV, blockIdx.x >> 5, blockIdx.x & 31);
}

// ===========================================================================
extern "C" void kernel_launch(void* const* d_in, const int* in_sizes, int n_in,
                              void* d_out, int out_size, void* d_ws, size_t ws_size,
                              hipStream_t stream)
{
    const float* z   = (const float*)d_in[1];
    const float* Kin = (const float*)d_in[2];
    const float* Vin = (const float*)d_in[3];
    const float* Wq  = (const float*)d_in[4];
    const float* bq  = (const float*)d_in[5];
    const float* Wk  = (const float*)d_in[6];
    const float* bk  = (const float*)d_in[7];
    const float* Wv  = (const float*)d_in[8];
    const float* bv  = (const float*)d_in[9];
    const float* W1  = (const float*)d_in[10];
    const float* b1  = (const float*)d_in[11];
    const float* W2  = (const float*)d_in[12];
    const float* b2  = (const float*)d_in[13];

    float* out   = (float*)d_out;
    float* o_dz  = out;
    float* o_da  = out + BD;
    float* o_dc  = out + BD + BB;
    float* o_dK  = out + 2 * BD + BB;
    float* o_dV  = out + 3 * BD + BB;

    float* ws    = (float*)d_ws;
    float* ws_v  = ws;
    float* ws_q  = ws + BD;
    float* ws_dq = ws + 2 * BD;
    float* ws_h  = ws + 3 * BD + 64;     // fallback only
    u16*   zb    = (u16*)(ws + 4 * BD + 64);
    u16*   hb    = zb + BD;
    u16*   dzb   = hb + BD;
    u16*   wt    = dzb + BD;             // 5 * WN u16

    // bf16 path floats needed (no partial pool anymore)
    const size_t pre_fl = 4ull * BD + 64 + (3ull * BD + 5ull * WN) / 2;

    dim3 blk(256);

    if (pre_fl * 4ull <= ws_size) {
        // ------------------- bf16 MFMA path: 5 dispatches -------------------
        u16* W1t = wt;
        u16* W2t = wt + 1ull * WN;
        u16* Wkt = wt + 2ull * WN;
        u16* Wvt = wt + 3ull * WN;
        u16* Wqt = wt + 4ull * WN;

        // 0) convert W1, Wk, Wv, z
        wconv1<<<dim3(32, 32, 4), blk, 0, stream>>>(
            W1, Wk, Wv, W1t, Wkt, Wvt, z, zb);

        // 1) gemm_h | gemm_k | gemm_v (full-K, in-block epilogue) ∥ wconv W2,Wq
        mA<<<dim3(96 + 2048), blk, 0, stream>>>(
            zb, W1t, Wkt, Wvt, b1, bk, bv, hb, o_dK, ws_v, W2, Wq, W2t, Wqt);

        // 2) gemm_dz ∥ dv_write b<32
        mDZ<<<dim3(32 + 1024), blk, 0, stream>>>(
            hb, W2t, b2, o_dz, dzb, ws_v, o_dK, o_dV);

        // 3) dual gemm_q ∥ dv_write b>=32
        mQ<<<dim3(32 + 1024), blk, 0, stream>>>(
            zb, dzb, Wqt, bq, ws_q, ws_dq, ws_v, o_dK, o_dV);
    } else {
        // ------------------- f32 fallback path -------------------
        float* pool = ws + 4 * BD + 64;
        int KSf = 16;
        while (KSf > 1 &&
               ((size_t)(4 * BD + 64) + 2ull * KSf * BD) * 4ull > ws_size)
            KSf >>= 1;
        int kc = DD / KSf;
        float* p0 = pool;
        float* p1 = pool + (size_t)KSf * BD;

        dim3 gG(DD / 64, KSf);
        dim3 gG2(DD / 64, KSf, 2);
        dim3 gE(BD / 256);

        gemm64<<<gG, blk, 0, stream>>>(z, W1, p0, kc);
        epilogue_f32<<<gE, blk, 0, stream>>>(p0, b1, ws_h, 1, KSf);

        gemm64<<<gG, blk, 0, stream>>>(ws_h, W2, p0, kc);
        epilogue_f32<<<gE, blk, 0, stream>>>(p0, b2, o_dz, 0, KSf);

        gemm64_z2<<<gG2, blk, 0, stream>>>(z, Wk, Wv, p0, p1, kc);
        ep_kv_f32<<<gE, blk, 0, stream>>>(p0, p1, bk, bv, o_dK, ws_v, KSf);

        dv_write_full<<<dim3(BB * 32), blk, 0, stream>>>(ws_v, o_dK, o_dV);

        gemm128<<<gG, blk, 0, stream>>>(z, o_dz, Wq, p0, kc);
        ep_q_dq_f32<<<gE, blk, 0, stream>>>(p0, bq, ws_q, ws_dq, KSf);
    }

    // final: dc = v*a + V@dq (pure read stream); also computes a, da in-block
    dc_fin<<<dim3(BB * 32), blk, 0, stream>>>(
        Vin, ws_v, ws_q, o_dK, ws_dq, Kin, o_da, o_dc);
}

// Round 8
// 411.456 us; speedup vs baseline: 1.2969x; 1.0005x over previous
//
#include <hip/hip_runtime.h>
#include <cstddef>
#include <math.h>

#define BB 64
#define DD 2048
#define HH 2048
#define BD (BB*DD)   // 131072
#define WN (2048*2048)

typedef unsigned short u16;
typedef __attribute__((ext_vector_type(8))) short bf16x8;
typedef __attribute__((ext_vector_type(4))) float f32x4;
typedef __attribute__((ext_vector_type(4))) float f4;

__device__ __forceinline__ u16 f2b(float x) {
    union { float f; unsigned u; } v; v.f = x;
    unsigned r = v.u + 0x7FFFu + ((v.u >> 16) & 1u);
    return (u16)(r >> 16);
}

__device__ __forceinline__ void gload16(const void* g, void* l) {
    __builtin_amdgcn_global_load_lds(
        (__attribute__((address_space(1))) void*)g,
        (__attribute__((address_space(3))) void*)l, 16, 0, 0);
}

// ===========================================================================
// shared device bodies
// ===========================================================================

// weight tile f32[k][n] -> bf16 T[n][k]; sm >= 64*66 u16
__device__ __forceinline__ void wconv_tile(
    u16* sm, const float* __restrict__ W, u16* __restrict__ T,
    int kb, int nb)
{
    int t = threadIdx.x;
    int k0 = kb * 64, n0 = nb * 64;
    {
        int r = t >> 2, c0 = (t & 3) * 16;
        const float* src = W + (size_t)(k0 + r) * DD + n0 + c0;
#pragma unroll
        for (int q = 0; q < 4; ++q) {
            float4 f = *(const float4*)(src + q * 4);
            sm[r * 66 + c0 + q*4 + 0] = f2b(f.x);
            sm[r * 66 + c0 + q*4 + 1] = f2b(f.y);
            sm[r * 66 + c0 + q*4 + 2] = f2b(f.z);
            sm[r * 66 + c0 + q*4 + 3] = f2b(f.w);
        }
    }
    __syncthreads();
    {
        int rn = t >> 2, ck = (t & 3) * 16;
        u16 o[16];
#pragma unroll
        for (int j = 0; j < 16; ++j) o[j] = sm[(ck + j) * 66 + rn];
        u16* dst = T + (size_t)(n0 + rn) * DD + k0 + ck;
        *(bf16x8*)dst       = *(bf16x8*)&o[0];
        *(bf16x8*)(dst + 8) = *(bf16x8*)&o[8];
    }
}

// ---- full-K (K=2048) 64x64 MFMA GEMM, 3-buffer 2-ahead pipeline.
// NS = # A-streams (1 or 2). sm: 3 * (NS+1) * 2048 u16.
// Counted vmcnt + raw s_barrier: prefetch stays in flight across barriers.
template<int NS>
__device__ __forceinline__ void gemm_fullk(
    u16* sm, const u16* __restrict__ A0, const u16* __restrict__ A1,
    const u16* __restrict__ Wt, int nblk, f32x4* acc0, f32x4* acc1)
{
    constexpr int NS1 = NS + 1;
    constexpr int REG = NS1 * 2048;      // u16 per buffer
    const int t = threadIdx.x, w = t >> 6, lane = t & 63;
    const int n0 = nblk * 64;
    const int srow = lane >> 2;          // 0..15
    const int sk   = (lane & 3) * 8;     // u16 offset, 16B chunks

    const u16* gA0 = A0 + (size_t)(w * 16 + srow) * DD + sk;
    const u16* gA1 = (NS == 2) ? A1 + (size_t)(w * 16 + srow) * DD + sk : A0;
    const u16* gW  = Wt + (size_t)(n0 + w * 16 + srow) * DD + sk;
    const int woff = w * 512;

    const int lane15 = lane & 15;
    const int k8 = (lane >> 4) * 8;

    auto stage = [&](int it, int buf) {
        u16* base = sm + buf * REG;
        gload16(gA0 + it * 32, base + woff);
        if constexpr (NS == 2) gload16(gA1 + it * 32, base + 2048 + woff);
        gload16(gW + it * 32, base + (NS1 - 1) * 2048 + woff);
    };

    constexpr int nt = DD / 32;          // 64
    stage(0, 0);
    stage(1, 1);
    for (int it = 0; it < nt; ++it) {
        const int cur = it % 3;
        if (it + 2 < nt) {
            stage(it + 2, (it + 2) % 3);
            if constexpr (NS == 1) asm volatile("s_waitcnt vmcnt(4)" ::: "memory");
            else                   asm volatile("s_waitcnt vmcnt(6)" ::: "memory");
        } else if (it + 1 < nt) {
            if constexpr (NS == 1) asm volatile("s_waitcnt vmcnt(2)" ::: "memory");
            else                   asm volatile("s_waitcnt vmcnt(3)" ::: "memory");
        } else {
            asm volatile("s_waitcnt vmcnt(0)" ::: "memory");
        }
        __builtin_amdgcn_s_barrier();

        const u16* base = sm + cur * REG;
        bf16x8 bfrag = *(const bf16x8*)&base[(NS1-1)*2048 + (w*16 + lane15)*32 + k8];
#pragma unroll
        for (int mt = 0; mt < 4; ++mt) {
            bf16x8 a0 = *(const bf16x8*)&base[(mt*16 + lane15)*32 + k8];
            acc0[mt] = __builtin_amdgcn_mfma_f32_16x16x32_bf16(a0, bfrag, acc0[mt], 0, 0, 0);
        }
        if constexpr (NS == 2) {
#pragma unroll
            for (int mt = 0; mt < 4; ++mt) {
                bf16x8 a1 = *(const bf16x8*)&base[2048 + (mt*16 + lane15)*32 + k8];
                acc1[mt] = __builtin_amdgcn_mfma_f32_16x16x32_bf16(a1, bfrag, acc1[mt], 0, 0, 0);
            }
        }
        __builtin_amdgcn_s_barrier();
    }
}

// ---- dV row-chunk writer: dV[b, chunk*64 .. +64, :] = v ⊗ dK (nt stores)
__device__ __forceinline__ void dv_body(
    const float* __restrict__ v, const float* __restrict__ dK,
    float* __restrict__ dV, int b, int chunk)
{
    int wave = threadIdx.x >> 6;
    int lane = threadIdx.x & 63;

    const f4* dK4 = (const f4*)(dK + ((size_t)b << 11));
    f4 dKr[8];
#pragma unroll
    for (int u = 0; u < 8; ++u) dKr[u] = dK4[u * 64 + lane];

    int row0 = chunk * 64 + wave * 16;
    for (int rr = 0; rr < 16; ++rr) {
        int row = row0 + rr;
        float vr = v[((size_t)b << 11) + row];
        f4* dV4 = (f4*)(dV + (((size_t)((b << 11) | row)) << 11));
#pragma unroll
        for (int u = 0; u < 8; ++u) {
            f4 o = vr * dKr[u];
            __builtin_nontemporal_store(o, &dV4[u * 64 + lane]);
        }
    }
}

// ===========================================================================
// bf16-path kernels
// ===========================================================================

// k_pre: convert W1, Wk, Wv (z=0..2) and z->bf16 (z=3)
__global__ __launch_bounds__(256) void wconv1(
    const float* __restrict__ W1, const float* __restrict__ Wk,
    const float* __restrict__ Wv, u16* __restrict__ W1t,
    u16* __restrict__ Wkt, u16* __restrict__ Wvt,
    const float* __restrict__ z, u16* __restrict__ zb)
{
    __shared__ u16 sm[64 * 66];
    int t = threadIdx.x;
    if (blockIdx.z == 3) {
        if (blockIdx.y != 0 || blockIdx.x >= 32) return;
        int i0 = blockIdx.x * 4096 + t * 16;
        u16 o[16];
#pragma unroll
        for (int q = 0; q < 4; ++q) {
            float4 f = *(const float4*)&z[i0 + q * 4];
            o[q*4+0] = f2b(f.x); o[q*4+1] = f2b(f.y);
            o[q*4+2] = f2b(f.z); o[q*4+3] = f2b(f.w);
        }
        *(bf16x8*)&zb[i0]     = *(bf16x8*)&o[0];
        *(bf16x8*)&zb[i0 + 8] = *(bf16x8*)&o[8];
        return;
    }
    const float* W = (blockIdx.z == 0) ? W1 : (blockIdx.z == 1) ? Wk : Wv;
    u16* T = (blockIdx.z == 0) ? W1t : (blockIdx.z == 1) ? Wkt : Wvt;
    wconv_tile(sm, W, T, blockIdx.x, blockIdx.y);
}

// mA: [0,32) gemm_h | [32,64) gemm_k | [64,96) gemm_v | [96,2144) wconv W2,Wq
__global__ __launch_bounds__(256) void mA(
    const u16* __restrict__ zb, const u16* __restrict__ W1t,
    const u16* __restrict__ Wkt, const u16* __restrict__ Wvt,
    const float* __restrict__ b1, const float* __restrict__ bk,
    const float* __restrict__ bv, u16* __restrict__ hb,
    float* __restrict__ dKo, float* __restrict__ vo,
    const float* __restrict__ W2, const float* __restrict__ Wq,
    u16* __restrict__ W2t, u16* __restrict__ Wqt)
{
    __shared__ u16 sm[3 * 4096];         // 24 KB
    int blk = blockIdx.x;
    if (blk < 96) {
        int sel  = blk >> 5;
        int nblk = blk & 31;
        const u16* Wt = (sel == 0) ? W1t : (sel == 1) ? Wkt : Wvt;
        f32x4 acc[4];
#pragma unroll
        for (int mt = 0; mt < 4; ++mt) acc[mt] = (f32x4){0.f,0.f,0.f,0.f};
        gemm_fullk<1>(sm, zb, zb, Wt, nblk, acc, nullptr);

        int w = threadIdx.x >> 6, lane = threadIdx.x & 63;
        int col = nblk * 64 + w * 16 + (lane & 15);
        int r4  = (lane >> 4) * 4;
        if (sel == 0) {
            float bb = b1[col];
#pragma unroll
            for (int mt = 0; mt < 4; ++mt)
#pragma unroll
                for (int j = 0; j < 4; ++j)
                    hb[(size_t)(mt*16 + r4 + j) * DD + col] =
                        f2b(tanhf(acc[mt][j] + bb));
        } else if (sel == 1) {
            float bb = bk[col];
#pragma unroll
            for (int mt = 0; mt < 4; ++mt)
#pragma unroll
                for (int j = 0; j < 4; ++j)
                    dKo[(size_t)(mt*16 + r4 + j) * DD + col] =
                        expf(acc[mt][j] + bb);
        } else {
            float bb = bv[col];
#pragma unroll
            for (int mt = 0; mt < 4; ++mt)
#pragma unroll
                for (int j = 0; j < 4; ++j)
                    vo[(size_t)(mt*16 + r4 + j) * DD + col] =
                        acc[mt][j] + bb;
        }
    } else {
        int r = blk - 96;                // 0..2047
        const float* W = (r < 1024) ? W2 : Wq;
        u16* T         = (r < 1024) ? W2t : Wqt;
        int rr = r & 1023;
        wconv_tile(sm, W, T, rr & 31, rr >> 5);
    }
}

// mDZ: [0,32) gemm_dz (full-K, writes dz f32 + dzb bf16) | [32,1056) dv b<32
__global__ __launch_bounds__(256) void mDZ(
    const u16* __restrict__ hb, const u16* __restrict__ W2t,
    const float* __restrict__ b2, float* __restrict__ dz,
    u16* __restrict__ dzb,
    const float* __restrict__ v, const float* __restrict__ dK,
    float* __restrict__ dV)
{
    __shared__ u16 sm[3 * 4096];         // 24 KB
    int blk = blockIdx.x;
    if (blk < 32) {
        f32x4 acc[4];
#pragma unroll
        for (int mt = 0; mt < 4; ++mt) acc[mt] = (f32x4){0.f,0.f,0.f,0.f};
        gemm_fullk<1>(sm, hb, hb, W2t, blk, acc, nullptr);

        int w = threadIdx.x >> 6, lane = threadIdx.x & 63;
        int col = blk * 64 + w * 16 + (lane & 15);
        int r4  = (lane >> 4) * 4;
        float bb = b2[col];
#pragma unroll
        for (int mt = 0; mt < 4; ++mt)
#pragma unroll
            for (int j = 0; j < 4; ++j) {
                float s = acc[mt][j] + bb;
                size_t idx = (size_t)(mt*16 + r4 + j) * DD + col;
                dz[idx]  = s;
                dzb[idx] = f2b(s);
            }
    } else {
        int r = blk - 32;
        dv_body(v, dK, dV, r >> 5, r & 31);
    }
}

// mQ: [0,32) dual gemm_q (z@Wq and dz@Wq share B-frag) | [32,1056) dv b>=32
__global__ __launch_bounds__(256) void mQ(
    const u16* __restrict__ zb, const u16* __restrict__ dzb,
    const u16* __restrict__ Wqt, const float* __restrict__ bq,
    float* __restrict__ qo, float* __restrict__ dqo,
    const float* __restrict__ v, const float* __restrict__ dK,
    float* __restrict__ dV)
{
    __shared__ u16 sm[3 * 6144];         // 36 KB
    int blk = blockIdx.x;
    if (blk < 32) {
        f32x4 az[4], ad[4];
#pragma unroll
        for (int mt = 0; mt < 4; ++mt) {
            az[mt] = (f32x4){0.f,0.f,0.f,0.f};
            ad[mt] = (f32x4){0.f,0.f,0.f,0.f};
        }
        gemm_fullk<2>(sm, zb, dzb, Wqt, blk, az, ad);

        int w = threadIdx.x >> 6, lane = threadIdx.x & 63;
        int col = blk * 64 + w * 16 + (lane & 15);
        int r4  = (lane >> 4) * 4;
        float bb = bq[col];
#pragma unroll
        for (int mt = 0; mt < 4; ++mt)
#pragma unroll
            for (int j = 0; j < 4; ++j) {
                float qv = expf(az[mt][j] + bb);
                size_t idx = (size_t)(mt*16 + r4 + j) * DD + col;
                qo[idx]  = qv;
                dqo[idx] = qv * (ad[mt][j] + bb);
            }
    } else {
        int r = blk - 32;
        dv_body(v, dK, dV, 32 + (r >> 5), r & 31);
    }
}

// a[b] = q . dK ; da[b] = a[b] + dq . K     (one block per batch, L2-hot)
__global__ __launch_bounds__(256) void reduce_a_da(
    const float* __restrict__ q, const float* __restrict__ dK,
    const float* __restrict__ dq, const float* __restrict__ Kin,
    float* __restrict__ a_ws, float* __restrict__ da_out)
{
    int b = blockIdx.x;
    int t = threadIdx.x;
    const float* qb  = q   + (size_t)b * DD;
    const float* dKb = dK  + (size_t)b * DD;
    const float* dqb = dq  + (size_t)b * DD;
    const float* Kb  = Kin + (size_t)b * DD;

    float s1 = 0.f, s2 = 0.f;
    for (int i = t; i < DD; i += 256) {
        s1 = fmaf(qb[i],  dKb[i], s1);
        s2 = fmaf(dqb[i], Kb[i],  s2);
    }
#pragma unroll
    for (int off = 32; off; off >>= 1) {
        s1 += __shfl_down(s1, off);
        s2 += __shfl_down(s2, off);
    }
    __shared__ float r1[4], r2[4];
    if ((t & 63) == 0) { r1[t >> 6] = s1; r2[t >> 6] = s2; }
    __syncthreads();
    if (t == 0) {
        float a  = r1[0] + r1[1] + r1[2] + r1[3];
        float k2 = r2[0] + r2[1] + r2[2] + r2[3];
        a_ws[b]   = a;
        da_out[b] = a + k2;
    }
}

// pure read stream: dc[b,d] = v[b,d]*a[b] + sum_e V[b,d,e]*dq[b,e]
__global__ __launch_bounds__(256) void dc_dot(
    const float* __restrict__ V, const float* __restrict__ v,
    const float* __restrict__ dq, const float* __restrict__ a,
    float* __restrict__ dc)
{
    int b     = blockIdx.x >> 5;
    int chunk = blockIdx.x & 31;
    int wave  = threadIdx.x >> 6;
    int lane  = threadIdx.x & 63;

    const f4* dq4 = (const f4*)(dq + ((size_t)b << 11));
    f4 dqr[8];
#pragma unroll
    for (int u = 0; u < 8; ++u) dqr[u] = dq4[u * 64 + lane];
    float ab = a[b];

    int row0 = chunk * 64 + wave * 16;
    for (int g = 0; g < 4; ++g) {
        float dot[4];
#pragma unroll
        for (int r2i = 0; r2i < 4; ++r2i) {
            int row = row0 + g * 4 + r2i;
            const f4* V4 = (const f4*)(V + (((size_t)((b << 11) | row)) << 11));
            float d = 0.f;
#pragma unroll
            for (int u = 0; u < 8; ++u) {
                f4 Vv = __builtin_nontemporal_load(&V4[u * 64 + lane]);
                d += Vv[0] * dqr[u][0] + Vv[1] * dqr[u][1]
                   + Vv[2] * dqr[u][2] + Vv[3] * dqr[u][3];
            }
            dot[r2i] = d;
        }
#pragma unroll
        for (int r2i = 0; r2i < 4; ++r2i) {
            float d = dot[r2i];
#pragma unroll
            for (int s = 32; s; s >>= 1) d += __shfl_down(d, s);
            if (lane == 0) {
                int row = row0 + g * 4 + r2i;
                dc[((size_t)b << 11) + row] =
                    v[((size_t)b << 11) + row] * ab + d;
            }
        }
    }
}

// ===========================================================================
// f32 fallback GEMM path (used only if d_ws is small)
// ===========================================================================
template<int MT>
__device__ __forceinline__ void gemm_body_f32(
    const float* __restrict__ A0, const float* __restrict__ A1,
    const float* __restrict__ W, float* __restrict__ part, int kc)
{
    constexpr int KC = 32;
    constexpr int RT = MT / 16;
    __shared__ float As[KC][MT];
    __shared__ float Ws[KC][64];

    const int t  = threadIdx.x;
    const int n0 = blockIdx.x * 64;
    const int k0 = blockIdx.y * kc;
    const int i  = t >> 4;
    const int j  = t & 15;

    float acc[RT][4];
#pragma unroll
    for (int r = 0; r < RT; ++r)
#pragma unroll
        for (int c = 0; c < 4; ++c) acc[r][c] = 0.f;

    for (int kk0 = 0; kk0 < kc; kk0 += KC) {
        {
            int kk = t >> 3;
            int nn = (t & 7) << 3;
            const float* s = W + (size_t)(k0 + kk0 + kk) * DD + n0 + nn;
            *(float4*)&Ws[kk][nn]     = *(const float4*)s;
            *(float4*)&Ws[kk][nn + 4] = *(const float4*)(s + 4);
        }
        if constexpr (MT == 64) {
            int m  = t & 63;
            int kb = (t >> 6) << 3;
            const float* s = A0 + (size_t)m * DD + k0 + kk0 + kb;
            float4 a0 = *(const float4*)s;
            float4 a1 = *(const float4*)(s + 4);
            As[kb+0][m] = a0.x; As[kb+1][m] = a0.y;
            As[kb+2][m] = a0.z; As[kb+3][m] = a0.w;
            As[kb+4][m] = a1.x; As[kb+5][m] = a1.y;
            As[kb+6][m] = a1.z; As[kb+7][m] = a1.w;
        } else {
            int m  = t & 127;
            int kb = (t >> 7) << 4;
            const float* base = (m < 64) ? (A0 + (size_t)m * DD)
                                         : (A1 + (size_t)(m - 64) * DD);
            const float* s = base + k0 + kk0 + kb;
#pragma unroll
            for (int p = 0; p < 4; ++p) {
                float4 av = *(const float4*)(s + p * 4);
                As[kb+p*4+0][m] = av.x; As[kb+p*4+1][m] = av.y;
                As[kb+p*4+2][m] = av.z; As[kb+p*4+3][m] = av.w;
            }
        }
        __syncthreads();
#pragma unroll
        for (int kk = 0; kk < KC; ++kk) {
            float4 wv = *(float4*)&Ws[kk][j << 2];
#pragma unroll
            for (int rq = 0; rq < RT / 4; ++rq) {
                float4 av = *(float4*)&As[kk][i * RT + rq * 4];
                acc[rq*4+0][0] = fmaf(av.x, wv.x, acc[rq*4+0][0]);
                acc[rq*4+0][1] = fmaf(av.x, wv.y, acc[rq*4+0][1]);
                acc[rq*4+0][2] = fmaf(av.x, wv.z, acc[rq*4+0][2]);
                acc[rq*4+0][3] = fmaf(av.x, wv.w, acc[rq*4+0][3]);
                acc[rq*4+1][0] = fmaf(av.y, wv.x, acc[rq*4+1][0]);
                acc[rq*4+1][1] = fmaf(av.y, wv.y, acc[rq*4+1][1]);
                acc[rq*4+1][2] = fmaf(av.y, wv.z, acc[rq*4+1][2]);
                acc[rq*4+1][3] = fmaf(av.y, wv.w, acc[rq*4+1][3]);
                acc[rq*4+2][0] = fmaf(av.z, wv.x, acc[rq*4+2][0]);
                acc[rq*4+2][1] = fmaf(av.z, wv.y, acc[rq*4+2][1]);
                acc[rq*4+2][2] = fmaf(av.z, wv.z, acc[rq*4+2][2]);
                acc[rq*4+2][3] = fmaf(av.z, wv.w, acc[rq*4+2][3]);
                acc[rq*4+3][0] = fmaf(av.w, wv.x, acc[rq*4+3][0]);
                acc[rq*4+3][1] = fmaf(av.w, wv.y, acc[rq*4+3][1]);
                acc[rq*4+3][2] = fmaf(av.w, wv.z, acc[rq*4+3][2]);
                acc[rq*4+3][3] = fmaf(av.w, wv.w, acc[rq*4+3][3]);
            }
        }
        __syncthreads();
    }

    float* P = part + (size_t)blockIdx.y * MT * DD + n0 + (j << 2);
#pragma unroll
    for (int r = 0; r < RT; ++r)
        *(float4*)&P[(size_t)(i * RT + r) * DD] =
            make_float4(acc[r][0], acc[r][1], acc[r][2], acc[r][3]);
}

__global__ __launch_bounds__(256) void gemm64(
    const float* __restrict__ A, const float* __restrict__ W,
    float* __restrict__ part, int kc)
{ gemm_body_f32<64>(A, A, W, part, kc); }

__global__ __launch_bounds__(256) void gemm64_z2(
    const float* __restrict__ A,
    const float* __restrict__ W0, const float* __restrict__ W1,
    float* __restrict__ p0, float* __restrict__ p1, int kc)
{
    const float* W = blockIdx.z ? W1 : W0;
    float*       P = blockIdx.z ? p1 : p0;
    gemm_body_f32<64>(A, A, W, P, kc);
}

__global__ __launch_bounds__(256) void gemm128(
    const float* __restrict__ A0, const float* __restrict__ A1,
    const float* __restrict__ W, float* __restrict__ part, int kc)
{ gemm_body_f32<128>(A0, A1, W, part, kc); }

__global__ __launch_bounds__(256) void epilogue_f32(
    const float* __restrict__ part, const float* __restrict__ bias,
    float* __restrict__ out, int act, int KS)
{
    int i = blockIdx.x * 256 + threadIdx.x;
    float s = bias[i & (DD - 1)];
    for (int ks = 0; ks < KS; ++ks) s += part[(size_t)ks * BD + i];
    if (act == 1) s = tanhf(s);
    out[i] = s;
}

__global__ __launch_bounds__(256) void ep_kv_f32(
    const float* __restrict__ pk, const float* __restrict__ pv,
    const float* __restrict__ bk, const float* __restrict__ bv,
    float* __restrict__ dKo, float* __restrict__ vo, int KS)
{
    int i = blockIdx.x * 256 + threadIdx.x;
    int d = i & (DD - 1);
    float sk = 0.f, sv = 0.f;
    for (int ks = 0; ks < KS; ++ks) {
        sk += pk[(size_t)ks * BD + i];
        sv += pv[(size_t)ks * BD + i];
    }
    dKo[i] = expf(sk + bk[d]);
    vo[i]  = sv + bv[d];
}

__global__ __launch_bounds__(256) void ep_q_dq_f32(
    const float* __restrict__ pq, const float* __restrict__ bq,
    float* __restrict__ qo, float* __restrict__ dqo, int KS)
{
    int i = blockIdx.x * 256 + threadIdx.x;
    int b = i >> 11, d = i & (DD - 1);
    float sq = 0.f, sd = 0.f;
    for (int ks = 0; ks < KS; ++ks) {
        const float* P = pq + (size_t)ks * (128 * DD);
        sq += P[(size_t)b * DD + d];
        sd += P[(size_t)(b + 64) * DD + d];
    }
    float bb = bq[d];
    float qv = expf(sq + bb);
    qo[i]  = qv;
    dqo[i] = qv * (sd + bb);
}

__global__ __launch_bounds__(256) void dv_write_full(
    const float* __restrict__ v, const float* __restrict__ dK,
    float* __restrict__ dV)
{
    dv_body(v, dK, dV, blockIdx.x >> 5, blockIdx.x & 31);
}

// ===========================================================================
extern "C" void kernel_launch(void* const* d_in, const int* in_sizes, int n_in,
                              void* d_out, int out_size, void* d_ws, size_t ws_size,
                              hipStream_t stream)
{
    const float* z   = (const float*)d_in[1];
    const float* Kin = (const float*)d_in[2];
    const float* Vin = (const float*)d_in[3];
    const float* Wq  = (const float*)d_in[4];
    const float* bq  = (const float*)d_in[5];
    const float* Wk  = (const float*)d_in[6];
    const float* bk  = (const float*)d_in[7];
    const float* Wv  = (const float*)d_in[8];
    const float* bv  = (const float*)d_in[9];
    const float* W1  = (const float*)d_in[10];
    const float* b1  = (const float*)d_in[11];
    const float* W2  = (const float*)d_in[12];
    const float* b2  = (const float*)d_in[13];

    float* out   = (float*)d_out;
    float* o_dz  = out;
    float* o_da  = out + BD;
    float* o_dc  = out + BD + BB;
    float* o_dK  = out + 2 * BD + BB;
    float* o_dV  = out + 3 * BD + BB;

    float* ws    = (float*)d_ws;
    float* ws_v  = ws;
    float* ws_q  = ws + BD;
    float* ws_dq = ws + 2 * BD;
    float* ws_a  = ws + 3 * BD;          // 64
    float* ws_h  = ws + 3 * BD + 64;     // fallback only
    u16*   zb    = (u16*)(ws + 4 * BD + 64);
    u16*   hb    = zb + BD;
    u16*   dzb   = hb + BD;
    u16*   wt    = dzb + BD;             // 5 * WN u16

    // bf16 path floats needed (no partial pool)
    const size_t pre_fl = 4ull * BD + 64 + (3ull * BD + 5ull * WN) / 2;

    dim3 blk(256);

    if (pre_fl * 4ull <= ws_size) {
        // ------------------- bf16 MFMA path: 6 dispatches -------------------
        u16* W1t = wt;
        u16* W2t = wt + 1ull * WN;
        u16* Wkt = wt + 2ull * WN;
        u16* Wvt = wt + 3ull * WN;
        u16* Wqt = wt + 4ull * WN;

        // 0) convert W1, Wk, Wv, z
        wconv1<<<dim3(32, 32, 4), blk, 0, stream>>>(
            W1, Wk, Wv, W1t, Wkt, Wvt, z, zb);

        // 1) gemm_h | gemm_k | gemm_v (full-K, in-block epilogue) ∥ wconv W2,Wq
        mA<<<dim3(96 + 2048), blk, 0, stream>>>(
            zb, W1t, Wkt, Wvt, b1, bk, bv, hb, o_dK, ws_v, W2, Wq, W2t, Wqt);

        // 2) gemm_dz ∥ dv_write b<32
        mDZ<<<dim3(32 + 1024), blk, 0, stream>>>(
            hb, W2t, b2, o_dz, dzb, ws_v, o_dK, o_dV);

        // 3) dual gemm_q ∥ dv_write b>=32
        mQ<<<dim3(32 + 1024), blk, 0, stream>>>(
            zb, dzb, Wqt, bq, ws_q, ws_dq, ws_v, o_dK, o_dV);
    } else {
        // ------------------- f32 fallback path -------------------
        float* pool = ws + 4 * BD + 64;
        int KSf = 16;
        while (KSf > 1 &&
               ((size_t)(4 * BD + 64) + 2ull * KSf * BD) * 4ull > ws_size)
            KSf >>= 1;
        int kc = DD / KSf;
        float* p0 = pool;
        float* p1 = pool + (size_t)KSf * BD;

        dim3 gG(DD / 64, KSf);
        dim3 gG2(DD / 64, KSf, 2);
        dim3 gE(BD / 256);

        gemm64<<<gG, blk, 0, stream>>>(z, W1, p0, kc);
        epilogue_f32<<<gE, blk, 0, stream>>>(p0, b1, ws_h, 1, KSf);

        gemm64<<<gG, blk, 0, stream>>>(ws_h, W2, p0, kc);
        epilogue_f32<<<gE, blk, 0, stream>>>(p0, b2, o_dz, 0, KSf);

        gemm64_z2<<<gG2, blk, 0, stream>>>(z, Wk, Wv, p0, p1, kc);
        ep_kv_f32<<<gE, blk, 0, stream>>>(p0, p1, bk, bv, o_dK, ws_v, KSf);

        dv_write_full<<<dim3(BB * 32), blk, 0, stream>>>(ws_v, o_dK, o_dV);

        gemm128<<<gG, blk, 0, stream>>>(z, o_dz, Wq, p0, kc);
        ep_q_dq_f32<<<gE, blk, 0, stream>>>(p0, bq, ws_q, ws_dq, KSf);
    }

    // 4) a = q . dK ; da = a + dq . K   (tiny, L2-hot inputs)
    reduce_a_da<<<dim3(BB), blk, 0, stream>>>(ws_q, o_dK, ws_dq, Kin, ws_a, o_da);

    // 5) dc = v*a + V @ dq  — pure nt-read stream
    dc_dot<<<dim3(BB * 32), blk, 0, stream>>>(Vin, ws_v, ws_dq, ws_a, o_dc);
}